// Round 3
// baseline (1053.388 us; speedup 1.0000x reference)
//
#include <hip/hip_runtime.h>
#include <hip/hip_bf16.h>

// N=100000 nodes, D=64 feat, H=256 hidden, E=1000000 edges per relation.
#define N_NODES 100000
#define DIM 64
#define HID 256
#define E_EDGES 1000000
#define NODES_PER_BLOCK 8
#define MLP_BLOCKS (N_NODES / NODES_PER_BLOCK)      // 12500

// Binned aggregation: TILE nodes per bin; per-bin LDS fp32 accumulator tile.
#define TILE 240                                     // 240*64*4B = 61440B LDS (+cnt) < 64KB
#define NBINS 417                                    // ceil(100000/240)
#define CAP 3072                                     // bin capacity; mean 2400, sd~49 -> +13.7 sd
#define EPB 4096                                     // edges per bin_fill block
#define GEO_BLOCKS 245                               // ceil(E/EPB)

__device__ __forceinline__ float tanh_fast(float x) {
    x = fminf(fmaxf(x, -15.0f), 15.0f);
    float e = __expf(2.0f * x);
    return (e - 1.0f) / (e + 1.0f);
}

// ---------- Phase A: bin edges by dst tile (LDS hist + one global atomic per block*bin) ----
__global__ void bin_fill_kernel(const int* __restrict__ gs, const int* __restrict__ gd,
                                const int* __restrict__ ts, const int* __restrict__ td,
                                const float* __restrict__ tw,
                                int* __restrict__ gcount,
                                int* __restrict__ gbin, int2* __restrict__ tbin) {
    __shared__ int hist[NBINS];
    __shared__ int baseS[NBINS];
    __shared__ int cur[NBINS];
    int t = threadIdx.x;
    int blk = blockIdx.x;
    int rel = (blk >= GEO_BLOCKS) ? 1 : 0;
    int e0 = (rel ? blk - GEO_BLOCKS : blk) * EPB;
    const int* dstp = rel ? td : gd;

    for (int i = t; i < NBINS; i += 256) { hist[i] = 0; cur[i] = 0; }
    __syncthreads();

    #pragma unroll
    for (int j = 0; j < EPB / 256; ++j) {
        int e = e0 + j * 256 + t;
        if (e < E_EDGES) atomicAdd(&hist[dstp[e] / TILE], 1);
    }
    __syncthreads();

    // Reserve global space: one device atomic per nonzero bin per block.
    for (int i = t; i < NBINS; i += 256) {
        int h = hist[i];
        baseS[i] = (h > 0) ? (i * CAP + atomicAdd(&gcount[rel * NBINS + i], h)) : 0;
    }
    __syncthreads();

    if (!rel) {
        #pragma unroll
        for (int j = 0; j < EPB / 256; ++j) {
            int e = e0 + j * 256 + t;
            if (e < E_EDGES) {
                int d = dstp[e];
                int bin = d / TILE;
                int pos = atomicAdd(&cur[bin], 1);
                int idx = baseS[bin] + pos;
                if (idx < (bin + 1) * CAP)                      // overflow guard (P~0)
                    gbin[idx] = gs[e] | ((d - bin * TILE) << 20);
            }
        }
    } else {
        #pragma unroll
        for (int j = 0; j < EPB / 256; ++j) {
            int e = e0 + j * 256 + t;
            if (e < E_EDGES) {
                int d = dstp[e];
                int bin = d / TILE;
                int pos = atomicAdd(&cur[bin], 1);
                int idx = baseS[bin] + pos;
                if (idx < (bin + 1) * CAP)
                    tbin[idx] = make_int2(ts[e] | ((d - bin * TILE) << 20),
                                          __float_as_int(tw[e]));
            }
        }
    }
}

// ---------- Phase B: per-bin LDS-privatized segment sums (no global atomics) ----------
__global__ void __launch_bounds__(512) aggregate_kernel(
        const float* __restrict__ feat,
        const int* __restrict__ gbin, const int2* __restrict__ tbin,
        const int* __restrict__ gcount,
        float* __restrict__ out_geo, float* __restrict__ trans_out,
        int* __restrict__ cnt_out) {
    __shared__ float acc[TILE * DIM];      // 61440 B
    __shared__ int cntl[TILE];
    int b = blockIdx.x;
    int rel = (b >= NBINS) ? 1 : 0;
    int bin = rel ? b - NBINS : b;
    int node0 = bin * TILE;
    int nNodes = min(TILE, N_NODES - node0);
    int t = threadIdx.x, lane = t & 63, wave = t >> 6;

    for (int i = t; i < TILE * DIM; i += 512) acc[i] = 0.0f;
    if (t < TILE) cntl[t] = 0;
    __syncthreads();

    int nE = gcount[b];
    if (nE > CAP) nE = CAP;

    if (!rel) {
        const int* bp = gbin + (size_t)bin * CAP;
        int k = wave;
        for (; k + 24 < nE; k += 32) {                 // 4 gathers in flight per wave
            int p0 = bp[k], p1 = bp[k + 8], p2 = bp[k + 16], p3 = bp[k + 24];
            float v0 = feat[(size_t)(p0 & 0xFFFFF) * DIM + lane];
            float v1 = feat[(size_t)(p1 & 0xFFFFF) * DIM + lane];
            float v2 = feat[(size_t)(p2 & 0xFFFFF) * DIM + lane];
            float v3 = feat[(size_t)(p3 & 0xFFFFF) * DIM + lane];
            atomicAdd(&acc[(p0 >> 20) * DIM + lane], v0);
            atomicAdd(&acc[(p1 >> 20) * DIM + lane], v1);
            atomicAdd(&acc[(p2 >> 20) * DIM + lane], v2);
            atomicAdd(&acc[(p3 >> 20) * DIM + lane], v3);
            if (lane == 0) {
                atomicAdd(&cntl[p0 >> 20], 1);
                atomicAdd(&cntl[p1 >> 20], 1);
                atomicAdd(&cntl[p2 >> 20], 1);
                atomicAdd(&cntl[p3 >> 20], 1);
            }
        }
        for (; k < nE; k += 8) {
            int p = bp[k];
            float v = feat[(size_t)(p & 0xFFFFF) * DIM + lane];
            atomicAdd(&acc[(p >> 20) * DIM + lane], v);
            if (lane == 0) atomicAdd(&cntl[p >> 20], 1);
        }
    } else {
        const int2* bp = tbin + (size_t)bin * CAP;
        int k = wave;
        for (; k + 24 < nE; k += 32) {
            int2 p0 = bp[k], p1 = bp[k + 8], p2 = bp[k + 16], p3 = bp[k + 24];
            float v0 = feat[(size_t)(p0.x & 0xFFFFF) * DIM + lane] * __int_as_float(p0.y);
            float v1 = feat[(size_t)(p1.x & 0xFFFFF) * DIM + lane] * __int_as_float(p1.y);
            float v2 = feat[(size_t)(p2.x & 0xFFFFF) * DIM + lane] * __int_as_float(p2.y);
            float v3 = feat[(size_t)(p3.x & 0xFFFFF) * DIM + lane] * __int_as_float(p3.y);
            atomicAdd(&acc[(p0.x >> 20) * DIM + lane], v0);
            atomicAdd(&acc[(p1.x >> 20) * DIM + lane], v1);
            atomicAdd(&acc[(p2.x >> 20) * DIM + lane], v2);
            atomicAdd(&acc[(p3.x >> 20) * DIM + lane], v3);
        }
        for (; k < nE; k += 8) {
            int2 p = bp[k];
            float v = feat[(size_t)(p.x & 0xFFFFF) * DIM + lane] * __int_as_float(p.y);
            atomicAdd(&acc[(p.x >> 20) * DIM + lane], v);
        }
    }
    __syncthreads();

    int limit = nNodes * DIM;
    float* outp = (rel ? trans_out : out_geo) + (size_t)node0 * DIM;
    for (int i = t; i < limit; i += 512) outp[i] = acc[i];
    if (!rel && t < nNodes) cnt_out[node0 + t] = cntl[t];
}

// ---------- Semantic-attention MLP ----------
__global__ void mlp_kernel(const float* __restrict__ geo_raw,
                           const float* __restrict__ trans,
                           const int* __restrict__ cnt,
                           const float* __restrict__ W1,
                           const float* __restrict__ b1,
                           const float* __restrict__ W2,
                           float* __restrict__ partials) {
    __shared__ float z_lds[DIM][20];
    __shared__ float wred[4][2];

    int t = threadIdx.x;
    int d = t & 63;
    int nlb = t >> 6;
    int node0 = blockIdx.x * NODES_PER_BLOCK;

    #pragma unroll
    for (int rep = 0; rep < 2; ++rep) {
        int nl = nlb * 2 + rep;
        int node = node0 + nl;
        float c = fmaxf((float)cnt[node], 1.0f);
        float g = geo_raw[node * DIM + d] * (1.0f / c);
        float tr = trans[node * DIM + d];
        z_lds[d][nl * 2 + 0] = g;
        z_lds[d][nl * 2 + 1] = tr;
    }
    __syncthreads();

    int j0 = (t & 63) << 2;
    int i0 = (t >> 6) << 2;

    float acc[4][4];
    #pragma unroll
    for (int a = 0; a < 4; ++a)
        #pragma unroll
        for (int b = 0; b < 4; ++b) acc[a][b] = 0.0f;

    #pragma unroll 8
    for (int dd = 0; dd < DIM; ++dd) {
        float4 zv = *(const float4*)&z_lds[dd][i0];
        float4 wv = *(const float4*)&W1[dd * HID + j0];
        acc[0][0] += zv.x * wv.x; acc[0][1] += zv.x * wv.y; acc[0][2] += zv.x * wv.z; acc[0][3] += zv.x * wv.w;
        acc[1][0] += zv.y * wv.x; acc[1][1] += zv.y * wv.y; acc[1][2] += zv.y * wv.z; acc[1][3] += zv.y * wv.w;
        acc[2][0] += zv.z * wv.x; acc[2][1] += zv.z * wv.y; acc[2][2] += zv.z * wv.z; acc[2][3] += zv.z * wv.w;
        acc[3][0] += zv.w * wv.x; acc[3][1] += zv.w * wv.y; acc[3][2] += zv.w * wv.z; acc[3][3] += zv.w * wv.w;
    }

    float c0 = 0.0f, c1 = 0.0f;
    #pragma unroll
    for (int jj = 0; jj < 4; ++jj) {
        int j = j0 + jj;
        float bj = b1[j];
        float w2j = W2[j];
        #pragma unroll
        for (int ii = 0; ii < 4; ++ii) {
            float h = tanh_fast(acc[ii][jj] + bj);
            if ((ii & 1) == 0) c0 += h * w2j;
            else               c1 += h * w2j;
        }
    }

    #pragma unroll
    for (int off = 32; off > 0; off >>= 1) {
        c0 += __shfl_down(c0, off);
        c1 += __shfl_down(c1, off);
    }
    int lane = t & 63, wv = t >> 6;
    if (lane == 0) { wred[wv][0] = c0; wred[wv][1] = c1; }
    __syncthreads();
    if (t == 0) {
        partials[blockIdx.x * 2 + 0] = wred[0][0] + wred[1][0] + wred[2][0] + wred[3][0];
        partials[blockIdx.x * 2 + 1] = wred[0][1] + wred[1][1] + wred[2][1] + wred[3][1];
    }
}

__global__ void beta_kernel(const float* __restrict__ partials, float* __restrict__ beta) {
    __shared__ float wred[4][2];
    int t = threadIdx.x;
    float c0 = 0.0f, c1 = 0.0f;
    for (int i = t; i < MLP_BLOCKS; i += 256) {
        c0 += partials[i * 2 + 0];
        c1 += partials[i * 2 + 1];
    }
    #pragma unroll
    for (int off = 32; off > 0; off >>= 1) {
        c0 += __shfl_down(c0, off);
        c1 += __shfl_down(c1, off);
    }
    int lane = t & 63, wv = t >> 6;
    if (lane == 0) { wred[wv][0] = c0; wred[wv][1] = c1; }
    __syncthreads();
    if (t == 0) {
        float s0 = (wred[0][0] + wred[1][0] + wred[2][0] + wred[3][0]) / (float)N_NODES;
        float s1 = (wred[0][1] + wred[1][1] + wred[2][1] + wred[3][1]) / (float)N_NODES;
        float m = fmaxf(s0, s1);
        float e0 = __expf(s0 - m), e1 = __expf(s1 - m);
        float inv = 1.0f / (e0 + e1);
        beta[0] = e0 * inv;
        beta[1] = e1 * inv;
    }
}

__global__ void combine_kernel(float* __restrict__ out_geo,
                               const float* __restrict__ trans,
                               const int* __restrict__ cnt,
                               const float* __restrict__ beta) {
    int gid = blockIdx.x * 256 + threadIdx.x;   // one float4 per thread
    int node = gid >> 4;
    float invc = 1.0f / fmaxf((float)cnt[node], 1.0f);
    float b0 = beta[0] * invc;
    float b1 = beta[1];
    float4 g = ((const float4*)out_geo)[gid];
    float4 tr = ((const float4*)trans)[gid];
    float4 o;
    o.x = b0 * g.x + b1 * tr.x;
    o.y = b0 * g.y + b1 * tr.y;
    o.z = b0 * g.z + b1 * tr.z;
    o.w = b0 * g.w + b1 * tr.w;
    ((float4*)out_geo)[gid] = o;
}

extern "C" void kernel_launch(void* const* d_in, const int* in_sizes, int n_in,
                              void* d_out, int out_size, void* d_ws, size_t ws_size,
                              hipStream_t stream) {
    const float* loc_feat = (const float*)d_in[0];
    const int* geo_src    = (const int*)d_in[1];
    const int* geo_dst    = (const int*)d_in[2];
    const int* trans_src  = (const int*)d_in[3];
    const int* trans_dst  = (const int*)d_in[4];
    const float* trans_w  = (const float*)d_in[5];
    const float* W1       = (const float*)d_in[6];
    const float* b1       = (const float*)d_in[7];
    const float* W2       = (const float*)d_in[8];
    float* out = (float*)d_out;

    // ws layout (4B units): [trans N*64][cnt N][gcount 2*NBINS][gbin NBINS*CAP]
    //                       [tbin NBINS*CAP int2][partials][beta]  ~= 41.5 MB
    float* trans    = (float*)d_ws;
    int*   cnt      = (int*)(trans + (size_t)N_NODES * DIM);
    int*   gcount   = cnt + N_NODES;
    int*   gbin     = gcount + 2 * NBINS;
    int2*  tbin     = (int2*)(gbin + (size_t)NBINS * CAP);
    float* partials = (float*)(tbin + (size_t)NBINS * CAP);
    float* beta     = partials + 2 * MLP_BLOCKS;

    hipMemsetAsync(gcount, 0, 2 * NBINS * sizeof(int), stream);

    bin_fill_kernel<<<2 * GEO_BLOCKS, 256, 0, stream>>>(geo_src, geo_dst, trans_src,
                                                        trans_dst, trans_w,
                                                        gcount, gbin, tbin);
    aggregate_kernel<<<2 * NBINS, 512, 0, stream>>>(loc_feat, gbin, tbin, gcount,
                                                    out, trans, cnt);
    mlp_kernel<<<MLP_BLOCKS, 256, 0, stream>>>(out, trans, cnt, W1, b1, W2, partials);
    beta_kernel<<<1, 256, 0, stream>>>(partials, beta);
    combine_kernel<<<(N_NODES * DIM / 4) / 256, 256, 0, stream>>>(out, trans, cnt, beta);
}

// Round 4
// 347.467 us; speedup vs baseline: 3.0316x; 3.0316x over previous
//
#include <hip/hip_runtime.h>
#include <hip/hip_bf16.h>

// N=100000 nodes, D=64 feat, H=256 hidden, E=1000000 edges per relation.
#define N_NODES 100000
#define DIM 64
#define HID 256
#define E_EDGES 1000000
#define NODES_PER_BLOCK 8
#define MLP_BLOCKS (N_NODES / NODES_PER_BLOCK)      // 12500

// Binned aggregation.
#define TILE 240                                     // nodes per bin
#define NBINS 417                                    // ceil(100000/240)
#define CAP 3072                                     // bin capacity; mean 2400, sd~49
#define EPB 4096                                     // edges per bin_fill block
#define GEO_BLOCKS 245                               // ceil(E/EPB)

__device__ __forceinline__ float tanh_fast(float x) {
    x = fminf(fmaxf(x, -15.0f), 15.0f);
    float e = __expf(2.0f * x);
    return (e - 1.0f) / (e + 1.0f);
}

// ---------- Phase A: bin edges by dst tile (LDS hist + one global atomic per block*bin) ----
__global__ void bin_fill_kernel(const int* __restrict__ gs, const int* __restrict__ gd,
                                const int* __restrict__ ts, const int* __restrict__ td,
                                const float* __restrict__ tw,
                                int* __restrict__ gcount,
                                int* __restrict__ gbin, int2* __restrict__ tbin) {
    __shared__ int hist[NBINS];
    __shared__ int baseS[NBINS];
    __shared__ int cur[NBINS];
    int t = threadIdx.x;
    int blk = blockIdx.x;
    int rel = (blk >= GEO_BLOCKS) ? 1 : 0;
    int e0 = (rel ? blk - GEO_BLOCKS : blk) * EPB;
    const int* dstp = rel ? td : gd;

    for (int i = t; i < NBINS; i += 256) { hist[i] = 0; cur[i] = 0; }
    __syncthreads();

    #pragma unroll
    for (int j = 0; j < EPB / 256; ++j) {
        int e = e0 + j * 256 + t;
        if (e < E_EDGES) atomicAdd(&hist[dstp[e] / TILE], 1);
    }
    __syncthreads();

    for (int i = t; i < NBINS; i += 256) {
        int h = hist[i];
        baseS[i] = (h > 0) ? (i * CAP + atomicAdd(&gcount[rel * NBINS + i], h)) : 0;
    }
    __syncthreads();

    if (!rel) {
        #pragma unroll
        for (int j = 0; j < EPB / 256; ++j) {
            int e = e0 + j * 256 + t;
            if (e < E_EDGES) {
                int d = dstp[e];
                int bin = d / TILE;
                int pos = atomicAdd(&cur[bin], 1);
                int idx = baseS[bin] + pos;
                if (idx < (bin + 1) * CAP)                      // overflow guard (P~0)
                    gbin[idx] = gs[e] | ((d - bin * TILE) << 20);
            }
        }
    } else {
        #pragma unroll
        for (int j = 0; j < EPB / 256; ++j) {
            int e = e0 + j * 256 + t;
            if (e < E_EDGES) {
                int d = dstp[e];
                int bin = d / TILE;
                int pos = atomicAdd(&cur[bin], 1);
                int idx = baseS[bin] + pos;
                if (idx < (bin + 1) * CAP)
                    tbin[idx] = make_int2(ts[e] | ((d - bin * TILE) << 20),
                                          __float_as_int(tw[e]));
            }
        }
    }
}

// ---------- Phase B: per-bin LDS counting sort + register-accumulated gather ----------
// No value-path atomics: scalar LDS atomics only for hist/cursor (1 per edge, not x64).
__global__ void __launch_bounds__(512) aggregate_kernel(
        const float* __restrict__ feat,
        const int* __restrict__ gbin, const int2* __restrict__ tbin,
        const int* __restrict__ gcount,
        float* __restrict__ out_geo, float* __restrict__ trans_out,
        int* __restrict__ cnt_out) {
    __shared__ int   srcS[CAP];      // 12 KB  sorted src ids
    __shared__ float wS[CAP];        // 12 KB  sorted weights (trans only)
    __shared__ int   histS[TILE];
    __shared__ int   baseS[TILE];
    __shared__ int   curS[TILE];
    __shared__ int   scanS[256];

    int b = blockIdx.x;
    int rel = (b >= NBINS) ? 1 : 0;
    int bin = rel ? b - NBINS : b;
    int node0 = bin * TILE;
    int nNodes = min(TILE, N_NODES - node0);
    int t = threadIdx.x, lane = t & 63, wave = t >> 6;

    int nE = gcount[b];
    if (nE > CAP) nE = CAP;

    for (int i = t; i < TILE; i += 512) histS[i] = 0;
    __syncthreads();

    // Pass 1: histogram over local dst (scalar LDS atomics).
    if (!rel) {
        const int* bp = gbin + (size_t)bin * CAP;
        for (int i = t; i < nE; i += 512) atomicAdd(&histS[bp[i] >> 20], 1);
    } else {
        const int2* bp = tbin + (size_t)bin * CAP;
        for (int i = t; i < nE; i += 512) atomicAdd(&histS[bp[i].x >> 20], 1);
    }
    __syncthreads();

    // Exclusive scan of histS (Hillis-Steele over 256 lanes; threads 256..511 idle but barrier).
    if (t < 256) scanS[t] = (t < TILE) ? histS[t] : 0;
    __syncthreads();
    #pragma unroll
    for (int off = 1; off < 256; off <<= 1) {
        int add = 0;
        if (t < 256 && t >= off) add = scanS[t - off];
        __syncthreads();
        if (t < 256) scanS[t] += add;
        __syncthreads();
    }
    if (t < TILE) {
        int base = scanS[t] - histS[t];
        baseS[t] = base;
        curS[t] = base;
    }
    __syncthreads();

    // Pass 2: place payload into sorted LDS lists.
    if (!rel) {
        const int* bp = gbin + (size_t)bin * CAP;
        for (int i = t; i < nE; i += 512) {
            int p = bp[i];
            int pos = atomicAdd(&curS[p >> 20], 1);
            srcS[pos] = p & 0xFFFFF;
        }
    } else {
        const int2* bp = tbin + (size_t)bin * CAP;
        for (int i = t; i < nE; i += 512) {
            int2 p = bp[i];
            int pos = atomicAdd(&curS[p.x >> 20], 1);
            srcS[pos] = p.x & 0xFFFFF;
            wS[pos] = __int_as_float(p.y);
        }
    }
    __syncthreads();

    // Pass 3: wave-per-node gather; lanes broadcast-read LDS src list (conflict-free),
    // 256B coalesced LLC gathers, register accumulate, one coalesced store per node.
    for (int nl = wave; nl < nNodes; nl += 8) {
        int deg = histS[nl];
        int base = baseS[nl];
        float acc = 0.0f;
        if (!rel) {
            int k = 0;
            for (; k + 3 < deg; k += 4) {
                int s0 = srcS[base + k], s1 = srcS[base + k + 1];
                int s2 = srcS[base + k + 2], s3 = srcS[base + k + 3];
                float v0 = feat[(size_t)s0 * DIM + lane];
                float v1 = feat[(size_t)s1 * DIM + lane];
                float v2 = feat[(size_t)s2 * DIM + lane];
                float v3 = feat[(size_t)s3 * DIM + lane];
                acc += (v0 + v1) + (v2 + v3);
            }
            for (; k < deg; ++k) acc += feat[(size_t)srcS[base + k] * DIM + lane];
            out_geo[(size_t)(node0 + nl) * DIM + lane] = acc;   // raw sum
        } else {
            int k = 0;
            for (; k + 3 < deg; k += 4) {
                int s0 = srcS[base + k], s1 = srcS[base + k + 1];
                int s2 = srcS[base + k + 2], s3 = srcS[base + k + 3];
                float w0 = wS[base + k], w1 = wS[base + k + 1];
                float w2 = wS[base + k + 2], w3 = wS[base + k + 3];
                float v0 = feat[(size_t)s0 * DIM + lane] * w0;
                float v1 = feat[(size_t)s1 * DIM + lane] * w1;
                float v2 = feat[(size_t)s2 * DIM + lane] * w2;
                float v3 = feat[(size_t)s3 * DIM + lane] * w3;
                acc += (v0 + v1) + (v2 + v3);
            }
            for (; k < deg; ++k)
                acc += feat[(size_t)srcS[base + k] * DIM + lane] * wS[base + k];
            trans_out[(size_t)(node0 + nl) * DIM + lane] = acc;
        }
    }
    if (!rel && t < nNodes) cnt_out[node0 + t] = histS[t];
}

// ---------- Semantic-attention MLP ----------
__global__ void mlp_kernel(const float* __restrict__ geo_raw,
                           const float* __restrict__ trans,
                           const int* __restrict__ cnt,
                           const float* __restrict__ W1,
                           const float* __restrict__ b1,
                           const float* __restrict__ W2,
                           float* __restrict__ partials) {
    __shared__ float z_lds[DIM][20];
    __shared__ float wred[4][2];

    int t = threadIdx.x;
    int d = t & 63;
    int nlb = t >> 6;
    int node0 = blockIdx.x * NODES_PER_BLOCK;

    #pragma unroll
    for (int rep = 0; rep < 2; ++rep) {
        int nl = nlb * 2 + rep;
        int node = node0 + nl;
        float c = fmaxf((float)cnt[node], 1.0f);
        float g = geo_raw[node * DIM + d] * (1.0f / c);
        float tr = trans[node * DIM + d];
        z_lds[d][nl * 2 + 0] = g;
        z_lds[d][nl * 2 + 1] = tr;
    }
    __syncthreads();

    int j0 = (t & 63) << 2;
    int i0 = (t >> 6) << 2;

    float acc[4][4];
    #pragma unroll
    for (int a = 0; a < 4; ++a)
        #pragma unroll
        for (int b = 0; b < 4; ++b) acc[a][b] = 0.0f;

    #pragma unroll 8
    for (int dd = 0; dd < DIM; ++dd) {
        float4 zv = *(const float4*)&z_lds[dd][i0];
        float4 wv = *(const float4*)&W1[dd * HID + j0];
        acc[0][0] += zv.x * wv.x; acc[0][1] += zv.x * wv.y; acc[0][2] += zv.x * wv.z; acc[0][3] += zv.x * wv.w;
        acc[1][0] += zv.y * wv.x; acc[1][1] += zv.y * wv.y; acc[1][2] += zv.y * wv.z; acc[1][3] += zv.y * wv.w;
        acc[2][0] += zv.z * wv.x; acc[2][1] += zv.z * wv.y; acc[2][2] += zv.z * wv.z; acc[2][3] += zv.z * wv.w;
        acc[3][0] += zv.w * wv.x; acc[3][1] += zv.w * wv.y; acc[3][2] += zv.w * wv.z; acc[3][3] += zv.w * wv.w;
    }

    float c0 = 0.0f, c1 = 0.0f;
    #pragma unroll
    for (int jj = 0; jj < 4; ++jj) {
        int j = j0 + jj;
        float bj = b1[j];
        float w2j = W2[j];
        #pragma unroll
        for (int ii = 0; ii < 4; ++ii) {
            float h = tanh_fast(acc[ii][jj] + bj);
            if ((ii & 1) == 0) c0 += h * w2j;
            else               c1 += h * w2j;
        }
    }

    #pragma unroll
    for (int off = 32; off > 0; off >>= 1) {
        c0 += __shfl_down(c0, off);
        c1 += __shfl_down(c1, off);
    }
    int lane = t & 63, wv = t >> 6;
    if (lane == 0) { wred[wv][0] = c0; wred[wv][1] = c1; }
    __syncthreads();
    if (t == 0) {
        partials[blockIdx.x * 2 + 0] = wred[0][0] + wred[1][0] + wred[2][0] + wred[3][0];
        partials[blockIdx.x * 2 + 1] = wred[0][1] + wred[1][1] + wred[2][1] + wred[3][1];
    }
}

__global__ void beta_kernel(const float* __restrict__ partials, float* __restrict__ beta) {
    __shared__ float wred[4][2];
    int t = threadIdx.x;
    float c0 = 0.0f, c1 = 0.0f;
    for (int i = t; i < MLP_BLOCKS; i += 256) {
        c0 += partials[i * 2 + 0];
        c1 += partials[i * 2 + 1];
    }
    #pragma unroll
    for (int off = 32; off > 0; off >>= 1) {
        c0 += __shfl_down(c0, off);
        c1 += __shfl_down(c1, off);
    }
    int lane = t & 63, wv = t >> 6;
    if (lane == 0) { wred[wv][0] = c0; wred[wv][1] = c1; }
    __syncthreads();
    if (t == 0) {
        float s0 = (wred[0][0] + wred[1][0] + wred[2][0] + wred[3][0]) / (float)N_NODES;
        float s1 = (wred[0][1] + wred[1][1] + wred[2][1] + wred[3][1]) / (float)N_NODES;
        float m = fmaxf(s0, s1);
        float e0 = __expf(s0 - m), e1 = __expf(s1 - m);
        float inv = 1.0f / (e0 + e1);
        beta[0] = e0 * inv;
        beta[1] = e1 * inv;
    }
}

__global__ void combine_kernel(float* __restrict__ out_geo,
                               const float* __restrict__ trans,
                               const int* __restrict__ cnt,
                               const float* __restrict__ beta) {
    int gid = blockIdx.x * 256 + threadIdx.x;   // one float4 per thread
    int node = gid >> 4;
    float invc = 1.0f / fmaxf((float)cnt[node], 1.0f);
    float b0 = beta[0] * invc;
    float b1 = beta[1];
    float4 g = ((const float4*)out_geo)[gid];
    float4 tr = ((const float4*)trans)[gid];
    float4 o;
    o.x = b0 * g.x + b1 * tr.x;
    o.y = b0 * g.y + b1 * tr.y;
    o.z = b0 * g.z + b1 * tr.z;
    o.w = b0 * g.w + b1 * tr.w;
    ((float4*)out_geo)[gid] = o;
}

extern "C" void kernel_launch(void* const* d_in, const int* in_sizes, int n_in,
                              void* d_out, int out_size, void* d_ws, size_t ws_size,
                              hipStream_t stream) {
    const float* loc_feat = (const float*)d_in[0];
    const int* geo_src    = (const int*)d_in[1];
    const int* geo_dst    = (const int*)d_in[2];
    const int* trans_src  = (const int*)d_in[3];
    const int* trans_dst  = (const int*)d_in[4];
    const float* trans_w  = (const float*)d_in[5];
    const float* W1       = (const float*)d_in[6];
    const float* b1       = (const float*)d_in[7];
    const float* W2       = (const float*)d_in[8];
    float* out = (float*)d_out;

    // ws layout (4B units): [trans N*64][cnt N][gcount 2*NBINS][gbin NBINS*CAP]
    //                       [tbin NBINS*CAP int2][partials][beta]  ~= 41.5 MB
    float* trans    = (float*)d_ws;
    int*   cnt      = (int*)(trans + (size_t)N_NODES * DIM);
    int*   gcount   = cnt + N_NODES;
    int*   gbin     = gcount + 2 * NBINS;
    int2*  tbin     = (int2*)(gbin + (size_t)NBINS * CAP);
    float* partials = (float*)(tbin + (size_t)NBINS * CAP);
    float* beta     = partials + 2 * MLP_BLOCKS;

    hipMemsetAsync(gcount, 0, 2 * NBINS * sizeof(int), stream);

    bin_fill_kernel<<<2 * GEO_BLOCKS, 256, 0, stream>>>(geo_src, geo_dst, trans_src,
                                                        trans_dst, trans_w,
                                                        gcount, gbin, tbin);
    aggregate_kernel<<<2 * NBINS, 512, 0, stream>>>(loc_feat, gbin, tbin, gcount,
                                                    out, trans, cnt);
    mlp_kernel<<<MLP_BLOCKS, 256, 0, stream>>>(out, trans, cnt, W1, b1, W2, partials);
    beta_kernel<<<1, 256, 0, stream>>>(partials, beta);
    combine_kernel<<<(N_NODES * DIM / 4) / 256, 256, 0, stream>>>(out, trans, cnt, beta);
}

// Round 5
// 261.744 us; speedup vs baseline: 4.0245x; 1.3275x over previous
//
#include <hip/hip_runtime.h>
#include <hip/hip_bf16.h>

// N=100000 nodes, D=64 feat, H=256 hidden, E=1000000 edges per relation.
#define N_NODES 100000
#define DIM 64
#define HID 256
#define E_EDGES 1000000
#define TWO_N (2 * N_NODES)
#define MLP_ROWBLOCKS (TWO_N / 64)                   // 3125 blocks of 64 z-rows

// Binned aggregation.
#define TILE 240                                     // nodes per bin
#define NBINS 417                                    // ceil(100000/240)
#define CAP 3072                                     // bin capacity; mean 2400, sd~49
#define EPB 4096                                     // edges per bin_fill block
#define GEO_BLOCKS 245                               // ceil(E/EPB)

typedef short short8 __attribute__((ext_vector_type(8)));   // 8 bf16 (4 VGPRs)
typedef float f32x4 __attribute__((ext_vector_type(4)));

__device__ __forceinline__ float tanh_fast(float x) {
    x = fminf(fmaxf(x, -15.0f), 15.0f);
    float e = __expf(2.0f * x);
    return (e - 1.0f) / (e + 1.0f);
}

__device__ __forceinline__ unsigned short f2bf(float x) {   // RNE f32->bf16
    unsigned u = __float_as_uint(x);
    u = u + 0x7FFFu + ((u >> 16) & 1u);
    return (unsigned short)(u >> 16);
}

// ---------- Phase A: bin edges by dst tile (LDS hist + one global atomic per block*bin) ----
__global__ void bin_fill_kernel(const int* __restrict__ gs, const int* __restrict__ gd,
                                const int* __restrict__ ts, const int* __restrict__ td,
                                const float* __restrict__ tw,
                                int* __restrict__ gcount,
                                int* __restrict__ gbin, int2* __restrict__ tbin) {
    __shared__ int hist[NBINS];
    __shared__ int baseS[NBINS];
    __shared__ int cur[NBINS];
    int t = threadIdx.x;
    int blk = blockIdx.x;
    int rel = (blk >= GEO_BLOCKS) ? 1 : 0;
    int e0 = (rel ? blk - GEO_BLOCKS : blk) * EPB;
    const int* dstp = rel ? td : gd;

    for (int i = t; i < NBINS; i += 256) { hist[i] = 0; cur[i] = 0; }
    __syncthreads();

    #pragma unroll
    for (int j = 0; j < EPB / 256; ++j) {
        int e = e0 + j * 256 + t;
        if (e < E_EDGES) atomicAdd(&hist[dstp[e] / TILE], 1);
    }
    __syncthreads();

    for (int i = t; i < NBINS; i += 256) {
        int h = hist[i];
        baseS[i] = (h > 0) ? (i * CAP + atomicAdd(&gcount[rel * NBINS + i], h)) : 0;
    }
    __syncthreads();

    if (!rel) {
        #pragma unroll
        for (int j = 0; j < EPB / 256; ++j) {
            int e = e0 + j * 256 + t;
            if (e < E_EDGES) {
                int d = dstp[e];
                int bin = d / TILE;
                int pos = atomicAdd(&cur[bin], 1);
                int idx = baseS[bin] + pos;
                if (idx < (bin + 1) * CAP)                      // overflow guard (P~0)
                    gbin[idx] = gs[e] | ((d - bin * TILE) << 20);
            }
        }
    } else {
        #pragma unroll
        for (int j = 0; j < EPB / 256; ++j) {
            int e = e0 + j * 256 + t;
            if (e < E_EDGES) {
                int d = dstp[e];
                int bin = d / TILE;
                int pos = atomicAdd(&cur[bin], 1);
                int idx = baseS[bin] + pos;
                if (idx < (bin + 1) * CAP)
                    tbin[idx] = make_int2(ts[e] | ((d - bin * TILE) << 20),
                                          __float_as_int(tw[e]));
            }
        }
    }
}

// ---------- Phase B: per-bin LDS counting sort + register-accumulated gather ----------
__global__ void __launch_bounds__(512) aggregate_kernel(
        const float* __restrict__ feat,
        const int* __restrict__ gbin, const int2* __restrict__ tbin,
        const int* __restrict__ gcount,
        float* __restrict__ out_geo, float* __restrict__ trans_out,
        int* __restrict__ cnt_out) {
    __shared__ int   srcS[CAP];      // 12 KB  sorted src ids
    __shared__ float wS[CAP];        // 12 KB  sorted weights (trans only)
    __shared__ int   histS[TILE];
    __shared__ int   baseS[TILE];
    __shared__ int   curS[TILE];
    __shared__ int   scanS[256];

    int b = blockIdx.x;
    int rel = (b >= NBINS) ? 1 : 0;
    int bin = rel ? b - NBINS : b;
    int node0 = bin * TILE;
    int nNodes = min(TILE, N_NODES - node0);
    int t = threadIdx.x, lane = t & 63, wave = t >> 6;

    int nE = gcount[b];
    if (nE > CAP) nE = CAP;

    for (int i = t; i < TILE; i += 512) histS[i] = 0;
    __syncthreads();

    // Pass 1: histogram over local dst (scalar LDS atomics).
    if (!rel) {
        const int* bp = gbin + (size_t)bin * CAP;
        for (int i = t; i < nE; i += 512) atomicAdd(&histS[bp[i] >> 20], 1);
    } else {
        const int2* bp = tbin + (size_t)bin * CAP;
        for (int i = t; i < nE; i += 512) atomicAdd(&histS[bp[i].x >> 20], 1);
    }
    __syncthreads();

    // Exclusive scan of histS.
    if (t < 256) scanS[t] = (t < TILE) ? histS[t] : 0;
    __syncthreads();
    #pragma unroll
    for (int off = 1; off < 256; off <<= 1) {
        int add = 0;
        if (t < 256 && t >= off) add = scanS[t - off];
        __syncthreads();
        if (t < 256) scanS[t] += add;
        __syncthreads();
    }
    if (t < TILE) {
        int base = scanS[t] - histS[t];
        baseS[t] = base;
        curS[t] = base;
    }
    __syncthreads();

    // Pass 2: place payload into sorted LDS lists.
    if (!rel) {
        const int* bp = gbin + (size_t)bin * CAP;
        for (int i = t; i < nE; i += 512) {
            int p = bp[i];
            int pos = atomicAdd(&curS[p >> 20], 1);
            srcS[pos] = p & 0xFFFFF;
        }
    } else {
        const int2* bp = tbin + (size_t)bin * CAP;
        for (int i = t; i < nE; i += 512) {
            int2 p = bp[i];
            int pos = atomicAdd(&curS[p.x >> 20], 1);
            srcS[pos] = p.x & 0xFFFFF;
            wS[pos] = __int_as_float(p.y);
        }
    }
    __syncthreads();

    // Pass 3: wave-per-node gather; register accumulate, one coalesced store per node.
    for (int nl = wave; nl < nNodes; nl += 8) {
        int deg = histS[nl];
        int base = baseS[nl];
        float acc = 0.0f;
        if (!rel) {
            int k = 0;
            for (; k + 3 < deg; k += 4) {
                int s0 = srcS[base + k], s1 = srcS[base + k + 1];
                int s2 = srcS[base + k + 2], s3 = srcS[base + k + 3];
                float v0 = feat[(size_t)s0 * DIM + lane];
                float v1 = feat[(size_t)s1 * DIM + lane];
                float v2 = feat[(size_t)s2 * DIM + lane];
                float v3 = feat[(size_t)s3 * DIM + lane];
                acc += (v0 + v1) + (v2 + v3);
            }
            for (; k < deg; ++k) acc += feat[(size_t)srcS[base + k] * DIM + lane];
            out_geo[(size_t)(node0 + nl) * DIM + lane] = acc;   // raw sum
        } else {
            int k = 0;
            for (; k + 3 < deg; k += 4) {
                int s0 = srcS[base + k], s1 = srcS[base + k + 1];
                int s2 = srcS[base + k + 2], s3 = srcS[base + k + 3];
                float w0 = wS[base + k], w1 = wS[base + k + 1];
                float w2 = wS[base + k + 2], w3 = wS[base + k + 3];
                float v0 = feat[(size_t)s0 * DIM + lane] * w0;
                float v1 = feat[(size_t)s1 * DIM + lane] * w1;
                float v2 = feat[(size_t)s2 * DIM + lane] * w2;
                float v3 = feat[(size_t)s3 * DIM + lane] * w3;
                acc += (v0 + v1) + (v2 + v3);
            }
            for (; k < deg; ++k)
                acc += feat[(size_t)srcS[base + k] * DIM + lane] * wS[base + k];
            trans_out[(size_t)(node0 + nl) * DIM + lane] = acc;
        }
    }
    if (!rel && t < nNodes) cnt_out[node0 + t] = histS[t];
}

// ---------- W1 -> bf16, packed in B-fragment order ----------
// W1p[(((n*2+khalf)*4+q)*16+nidx)*8+j] = bf16(W1[32*khalf+8*q+j][16*n+nidx])
__global__ void pack_w1_kernel(const float* __restrict__ W1, unsigned short* __restrict__ W1p) {
    int i = blockIdx.x * 256 + threadIdx.x;      // 0..16383
    int j = i & 7;
    int r = i >> 3;
    int nidx = r & 15; r >>= 4;
    int q = r & 3; r >>= 2;
    int khalf = r & 1;
    int n = r >> 1;
    int k = 32 * khalf + 8 * q + j;
    int c = 16 * n + nidx;
    W1p[i] = f2bf(W1[k * HID + c]);
}

// ---------- Semantic-attention MLP via bf16 MFMA ----------
// Rows R of z: R<N -> geo node R (scaled 1/cnt), else trans node R-N.
// Block = 64 rows; wave w owns rows [base, base+16). A[m=lane&15][k=quad*8+j].
__global__ void __launch_bounds__(256) mlp_mfma_kernel(
        const float* __restrict__ geo_raw, const float* __restrict__ trans,
        const int* __restrict__ cnt,
        const unsigned short* __restrict__ W1p,
        const float* __restrict__ bias1, const float* __restrict__ W2,
        float* __restrict__ partials) {
    __shared__ float wred[4][2];
    int t = threadIdx.x, lane = t & 63, wave = t >> 6;
    int m = lane & 15, q = lane >> 4;
    int base = blockIdx.x * 64 + wave * 16;
    int R = base + m;

    const float* rowp;
    float scale;
    if (R < N_NODES) {
        rowp = geo_raw + (size_t)R * DIM;
        scale = 1.0f / fmaxf((float)cnt[R], 1.0f);
    } else {
        rowp = trans + (size_t)(R - N_NODES) * DIM;
        scale = 1.0f;
    }

    // A fragments: khalf0 k=q*8.., khalf1 k=32+q*8..
    float4 v0 = *(const float4*)(rowp + q * 8);
    float4 v1 = *(const float4*)(rowp + q * 8 + 4);
    float4 v2 = *(const float4*)(rowp + 32 + q * 8);
    float4 v3 = *(const float4*)(rowp + 32 + q * 8 + 4);
    short8 a0, a1;
    a0[0] = (short)f2bf(v0.x * scale); a0[1] = (short)f2bf(v0.y * scale);
    a0[2] = (short)f2bf(v0.z * scale); a0[3] = (short)f2bf(v0.w * scale);
    a0[4] = (short)f2bf(v1.x * scale); a0[5] = (short)f2bf(v1.y * scale);
    a0[6] = (short)f2bf(v1.z * scale); a0[7] = (short)f2bf(v1.w * scale);
    a1[0] = (short)f2bf(v2.x * scale); a1[1] = (short)f2bf(v2.y * scale);
    a1[2] = (short)f2bf(v2.z * scale); a1[3] = (short)f2bf(v2.w * scale);
    a1[4] = (short)f2bf(v3.x * scale); a1[5] = (short)f2bf(v3.y * scale);
    a1[6] = (short)f2bf(v3.z * scale); a1[7] = (short)f2bf(v3.w * scale);

    float c0 = 0.0f, c1 = 0.0f;
    const short8* W1v = (const short8*)W1p;   // 512 frags of 8 bf16

    #pragma unroll 4
    for (int n = 0; n < 16; ++n) {
        short8 b0 = W1v[(n * 2 + 0) * 64 + lane];
        short8 bK = W1v[(n * 2 + 1) * 64 + lane];
        f32x4 acc = {0.0f, 0.0f, 0.0f, 0.0f};
        acc = __builtin_amdgcn_mfma_f32_16x16x32_bf16(a0, b0, acc, 0, 0, 0);
        acc = __builtin_amdgcn_mfma_f32_16x16x32_bf16(a1, bK, acc, 0, 0, 0);
        int col = 16 * n + m;                 // C/D: col=lane&15, row=q*4+reg
        float bj = bias1[col];
        float w2 = W2[col];
        #pragma unroll
        for (int reg = 0; reg < 4; ++reg) {
            int Rr = base + q * 4 + reg;
            float h = tanh_fast(acc[reg] + bj);
            float contrib = h * w2;
            if (Rr < N_NODES) c0 += contrib; else c1 += contrib;
        }
    }

    #pragma unroll
    for (int off = 32; off > 0; off >>= 1) {
        c0 += __shfl_down(c0, off);
        c1 += __shfl_down(c1, off);
    }
    if (lane == 0) { wred[wave][0] = c0; wred[wave][1] = c1; }
    __syncthreads();
    if (t == 0) {
        partials[blockIdx.x * 2 + 0] = wred[0][0] + wred[1][0] + wred[2][0] + wred[3][0];
        partials[blockIdx.x * 2 + 1] = wred[0][1] + wred[1][1] + wred[2][1] + wred[3][1];
    }
}

__global__ void beta_kernel(const float* __restrict__ partials, float* __restrict__ beta) {
    __shared__ float wred[4][2];
    int t = threadIdx.x;
    float c0 = 0.0f, c1 = 0.0f;
    for (int i = t; i < MLP_ROWBLOCKS; i += 256) {
        c0 += partials[i * 2 + 0];
        c1 += partials[i * 2 + 1];
    }
    #pragma unroll
    for (int off = 32; off > 0; off >>= 1) {
        c0 += __shfl_down(c0, off);
        c1 += __shfl_down(c1, off);
    }
    int lane = t & 63, wv = t >> 6;
    if (lane == 0) { wred[wv][0] = c0; wred[wv][1] = c1; }
    __syncthreads();
    if (t == 0) {
        float s0 = (wred[0][0] + wred[1][0] + wred[2][0] + wred[3][0]) / (float)N_NODES;
        float s1 = (wred[0][1] + wred[1][1] + wred[2][1] + wred[3][1]) / (float)N_NODES;
        float m = fmaxf(s0, s1);
        float e0 = __expf(s0 - m), e1 = __expf(s1 - m);
        float inv = 1.0f / (e0 + e1);
        beta[0] = e0 * inv;
        beta[1] = e1 * inv;
    }
}

__global__ void combine_kernel(float* __restrict__ out_geo,
                               const float* __restrict__ trans,
                               const int* __restrict__ cnt,
                               const float* __restrict__ beta) {
    int gid = blockIdx.x * 256 + threadIdx.x;   // one float4 per thread
    int node = gid >> 4;
    float invc = 1.0f / fmaxf((float)cnt[node], 1.0f);
    float b0 = beta[0] * invc;
    float b1 = beta[1];
    float4 g = ((const float4*)out_geo)[gid];
    float4 tr = ((const float4*)trans)[gid];
    float4 o;
    o.x = b0 * g.x + b1 * tr.x;
    o.y = b0 * g.y + b1 * tr.y;
    o.z = b0 * g.z + b1 * tr.z;
    o.w = b0 * g.w + b1 * tr.w;
    ((float4*)out_geo)[gid] = o;
}

extern "C" void kernel_launch(void* const* d_in, const int* in_sizes, int n_in,
                              void* d_out, int out_size, void* d_ws, size_t ws_size,
                              hipStream_t stream) {
    const float* loc_feat = (const float*)d_in[0];
    const int* geo_src    = (const int*)d_in[1];
    const int* geo_dst    = (const int*)d_in[2];
    const int* trans_src  = (const int*)d_in[3];
    const int* trans_dst  = (const int*)d_in[4];
    const float* trans_w  = (const float*)d_in[5];
    const float* W1       = (const float*)d_in[6];
    const float* b1       = (const float*)d_in[7];
    const float* W2       = (const float*)d_in[8];
    float* out = (float*)d_out;

    // ws layout (4B units): [trans N*64][cnt N][gcount 2*NBINS][gbin NBINS*CAP]
    //                       [tbin NBINS*CAP int2][partials 2*3125][beta 2][W1p 16384 u16]
    float* trans    = (float*)d_ws;
    int*   cnt      = (int*)(trans + (size_t)N_NODES * DIM);
    int*   gcount   = cnt + N_NODES;
    int*   gbin     = gcount + 2 * NBINS;
    int2*  tbin     = (int2*)(gbin + (size_t)NBINS * CAP);
    float* partials = (float*)(tbin + (size_t)NBINS * CAP);
    float* beta     = partials + 2 * MLP_ROWBLOCKS;
    unsigned short* W1p = (unsigned short*)(beta + 2);

    hipMemsetAsync(gcount, 0, 2 * NBINS * sizeof(int), stream);

    pack_w1_kernel<<<64, 256, 0, stream>>>(W1, W1p);
    bin_fill_kernel<<<2 * GEO_BLOCKS, 256, 0, stream>>>(geo_src, geo_dst, trans_src,
                                                        trans_dst, trans_w,
                                                        gcount, gbin, tbin);
    aggregate_kernel<<<2 * NBINS, 512, 0, stream>>>(loc_feat, gbin, tbin, gcount,
                                                    out, trans, cnt);
    mlp_mfma_kernel<<<MLP_ROWBLOCKS, 256, 0, stream>>>(out, trans, cnt, W1p, b1, W2, partials);
    beta_kernel<<<1, 256, 0, stream>>>(partials, beta);
    combine_kernel<<<(N_NODES * DIM / 4) / 256, 256, 0, stream>>>(out, trans, cnt, beta);
}

// Round 6
// 252.029 us; speedup vs baseline: 4.1796x; 1.0385x over previous
//
#include <hip/hip_runtime.h>
#include <hip/hip_bf16.h>

// N=100000 nodes, D=64 feat, H=256 hidden, E=1000000 edges per relation.
#define N_NODES 100000
#define DIM 64
#define HID 256
#define E_EDGES 1000000
#define TWO_N (2 * N_NODES)
#define MLP_ROWBLOCKS (TWO_N / 64)                   // 3125 blocks of 64 z-rows

// Binned aggregation.
#define TILE 240                                     // nodes per bin
#define NBINS 417                                    // ceil(100000/240)
#define CAP 3072                                     // bin capacity; mean 2400, sd~49
#define EPB 4096                                     // edges per bin_fill block
#define GEO_BLOCKS 245                               // ceil(E/EPB)

typedef short short8 __attribute__((ext_vector_type(8)));   // 8 bf16 (4 VGPRs)
typedef float f32x4 __attribute__((ext_vector_type(4)));
typedef unsigned short us4 __attribute__((ext_vector_type(4)));

__device__ __forceinline__ float tanh_fast(float x) {
    x = fminf(fmaxf(x, -15.0f), 15.0f);
    float e = __expf(2.0f * x);
    return (e - 1.0f) / (e + 1.0f);
}

__device__ __forceinline__ unsigned short f2bf(float x) {   // RNE f32->bf16
    unsigned u = __float_as_uint(x);
    u = u + 0x7FFFu + ((u >> 16) & 1u);
    return (unsigned short)(u >> 16);
}

// ---------- feat -> bf16 (gather working set 25.6 -> 12.8 MB) ----------
__global__ void pack_feat_kernel(const float* __restrict__ feat,
                                 unsigned short* __restrict__ fb) {
    int i = blockIdx.x * 256 + threadIdx.x;          // one float4 -> ushort4
    float4 v = ((const float4*)feat)[i];
    us4 o;
    o[0] = f2bf(v.x); o[1] = f2bf(v.y); o[2] = f2bf(v.z); o[3] = f2bf(v.w);
    ((us4*)fb)[i] = o;
}

// ---------- Phase A: bin edges by dst tile ----------
// int4-vectorized reads; dst cached in registers between hist and fill passes.
__global__ void bin_fill_kernel(const int* __restrict__ gs, const int* __restrict__ gd,
                                const int* __restrict__ ts, const int* __restrict__ td,
                                const float* __restrict__ tw,
                                int* __restrict__ gcount,
                                int* __restrict__ gbin, int2* __restrict__ tbin) {
    __shared__ int hist[NBINS];
    __shared__ int baseS[NBINS];
    __shared__ int cur[NBINS];
    int t = threadIdx.x;
    int blk = blockIdx.x;
    int rel = (blk >= GEO_BLOCKS) ? 1 : 0;
    int e0 = (rel ? blk - GEO_BLOCKS : blk) * EPB;
    const int* dstp = rel ? td : gd;
    const int* srcp = rel ? ts : gs;

    // Load 16 dst values (4 x int4), cache in registers.
    int dc[16];
    #pragma unroll
    for (int j = 0; j < 4; ++j) {
        int idx = e0 + j * 1024 + 4 * t;
        if (idx + 3 < E_EDGES) {
            int4 v = *(const int4*)&dstp[idx];
            dc[4 * j + 0] = v.x; dc[4 * j + 1] = v.y;
            dc[4 * j + 2] = v.z; dc[4 * j + 3] = v.w;
        } else {
            #pragma unroll
            for (int i2 = 0; i2 < 4; ++i2)
                dc[4 * j + i2] = (idx + i2 < E_EDGES) ? dstp[idx + i2] : -1;
        }
    }

    for (int i = t; i < NBINS; i += 256) { hist[i] = 0; cur[i] = 0; }
    __syncthreads();

    #pragma unroll
    for (int i = 0; i < 16; ++i)
        if (dc[i] >= 0) atomicAdd(&hist[dc[i] / TILE], 1);
    __syncthreads();

    // Reserve global space: one device atomic per nonzero bin per block.
    for (int i = t; i < NBINS; i += 256) {
        int h = hist[i];
        baseS[i] = (h > 0) ? (i * CAP + atomicAdd(&gcount[rel * NBINS + i], h)) : 0;
    }
    __syncthreads();

    if (!rel) {
        #pragma unroll
        for (int j = 0; j < 4; ++j) {
            int idx = e0 + j * 1024 + 4 * t;
            bool vec = (idx + 3 < E_EDGES);
            int4 sv = {0, 0, 0, 0};
            if (vec) sv = *(const int4*)&srcp[idx];
            int ss[4] = {sv.x, sv.y, sv.z, sv.w};
            #pragma unroll
            for (int i2 = 0; i2 < 4; ++i2) {
                int d = dc[4 * j + i2];
                if (d < 0) continue;
                int s = vec ? ss[i2] : srcp[idx + i2];
                int bin = d / TILE;
                int pos = atomicAdd(&cur[bin], 1);
                int gi = baseS[bin] + pos;
                if (gi < (bin + 1) * CAP)                       // overflow guard (P~0)
                    gbin[gi] = s | ((d - bin * TILE) << 20);
            }
        }
    } else {
        #pragma unroll
        for (int j = 0; j < 4; ++j) {
            int idx = e0 + j * 1024 + 4 * t;
            bool vec = (idx + 3 < E_EDGES);
            int4 sv = {0, 0, 0, 0};
            float4 wv = {0.f, 0.f, 0.f, 0.f};
            if (vec) {
                sv = *(const int4*)&srcp[idx];
                wv = *(const float4*)&tw[idx];
            }
            int ss[4] = {sv.x, sv.y, sv.z, sv.w};
            float ww[4] = {wv.x, wv.y, wv.z, wv.w};
            #pragma unroll
            for (int i2 = 0; i2 < 4; ++i2) {
                int d = dc[4 * j + i2];
                if (d < 0) continue;
                int s = vec ? ss[i2] : srcp[idx + i2];
                float w = vec ? ww[i2] : tw[idx + i2];
                int bin = d / TILE;
                int pos = atomicAdd(&cur[bin], 1);
                int gi = baseS[bin] + pos;
                if (gi < (bin + 1) * CAP)
                    tbin[gi] = make_int2(s | ((d - bin * TILE) << 20), __float_as_int(w));
            }
        }
    }
}

// ---------- Phase B: per-bin LDS counting sort + bf16 half-wave-pair gather ----------
__global__ void __launch_bounds__(512) aggregate_kernel(
        const unsigned short* __restrict__ featb,
        const int* __restrict__ gbin, const int2* __restrict__ tbin,
        const int* __restrict__ gcount,
        float* __restrict__ out_geo, float* __restrict__ trans_out,
        int* __restrict__ cnt_out) {
    __shared__ int   srcS[CAP];      // 12 KB  sorted src ids
    __shared__ float wS[CAP];        // 12 KB  sorted weights (trans only)
    __shared__ int   histS[TILE];
    __shared__ int   baseS[TILE];
    __shared__ int   curS[TILE];
    __shared__ int   scanS[256];

    int b = blockIdx.x;
    int rel = (b >= NBINS) ? 1 : 0;
    int bin = rel ? b - NBINS : b;
    int node0 = bin * TILE;
    int nNodes = min(TILE, N_NODES - node0);
    int t = threadIdx.x, lane = t & 63, wave = t >> 6;
    int half = lane >> 5, hl = lane & 31;            // half-wave id / lane-in-half

    int nE = gcount[b];
    if (nE > CAP) nE = CAP;

    for (int i = t; i < TILE; i += 512) histS[i] = 0;
    __syncthreads();

    // Pass 1: histogram over local dst (scalar LDS atomics).
    if (!rel) {
        const int* bp = gbin + (size_t)bin * CAP;
        for (int i = t; i < nE; i += 512) atomicAdd(&histS[bp[i] >> 20], 1);
    } else {
        const int2* bp = tbin + (size_t)bin * CAP;
        for (int i = t; i < nE; i += 512) atomicAdd(&histS[bp[i].x >> 20], 1);
    }
    __syncthreads();

    // Exclusive scan of histS.
    if (t < 256) scanS[t] = (t < TILE) ? histS[t] : 0;
    __syncthreads();
    #pragma unroll
    for (int off = 1; off < 256; off <<= 1) {
        int add = 0;
        if (t < 256 && t >= off) add = scanS[t - off];
        __syncthreads();
        if (t < 256) scanS[t] += add;
        __syncthreads();
    }
    if (t < TILE) {
        int base = scanS[t] - histS[t];
        baseS[t] = base;
        curS[t] = base;
    }
    __syncthreads();

    // Pass 2: place payload into sorted LDS lists.
    if (!rel) {
        const int* bp = gbin + (size_t)bin * CAP;
        for (int i = t; i < nE; i += 512) {
            int p = bp[i];
            int pos = atomicAdd(&curS[p >> 20], 1);
            srcS[pos] = p & 0xFFFFF;
        }
    } else {
        const int2* bp = tbin + (size_t)bin * CAP;
        for (int i = t; i < nE; i += 512) {
            int2 p = bp[i];
            int pos = atomicAdd(&curS[p.x >> 20], 1);
            srcS[pos] = p.x & 0xFFFFF;
            wS[pos] = __int_as_float(p.y);
        }
    }
    __syncthreads();

    // Pass 3: wave-per-node; edges in pairs (half 0 -> edge k, half 1 -> edge k+1);
    // each lane loads ushort2 (dims 2*hl, 2*hl+1) = 4B/lane, 128B/row. fp32 acc.
    for (int nl = wave; nl < nNodes; nl += 8) {
        int deg = histS[nl];
        int base = baseS[nl];
        float ax = 0.0f, ay = 0.0f;
        if (!rel) {
            int k = 0;
            for (; k + 7 < deg; k += 8) {            // 4 pair-loads in flight
                int s0 = srcS[base + k + half];
                int s1 = srcS[base + k + 2 + half];
                int s2 = srcS[base + k + 4 + half];
                int s3 = srcS[base + k + 6 + half];
                unsigned r0 = *(const unsigned*)&featb[(size_t)s0 * DIM + 2 * hl];
                unsigned r1 = *(const unsigned*)&featb[(size_t)s1 * DIM + 2 * hl];
                unsigned r2 = *(const unsigned*)&featb[(size_t)s2 * DIM + 2 * hl];
                unsigned r3 = *(const unsigned*)&featb[(size_t)s3 * DIM + 2 * hl];
                ax += __uint_as_float(r0 << 16) + __uint_as_float(r1 << 16)
                    + __uint_as_float(r2 << 16) + __uint_as_float(r3 << 16);
                ay += __uint_as_float(r0 & 0xFFFF0000u) + __uint_as_float(r1 & 0xFFFF0000u)
                    + __uint_as_float(r2 & 0xFFFF0000u) + __uint_as_float(r3 & 0xFFFF0000u);
            }
            for (; k + 1 < deg; k += 2) {
                int s = srcS[base + k + half];
                unsigned r = *(const unsigned*)&featb[(size_t)s * DIM + 2 * hl];
                ax += __uint_as_float(r << 16);
                ay += __uint_as_float(r & 0xFFFF0000u);
            }
            if (k < deg && half == 0) {
                int s = srcS[base + k];
                unsigned r = *(const unsigned*)&featb[(size_t)s * DIM + 2 * hl];
                ax += __uint_as_float(r << 16);
                ay += __uint_as_float(r & 0xFFFF0000u);
            }
        } else {
            int k = 0;
            for (; k + 7 < deg; k += 8) {
                int s0 = srcS[base + k + half];
                int s1 = srcS[base + k + 2 + half];
                int s2 = srcS[base + k + 4 + half];
                int s3 = srcS[base + k + 6 + half];
                float w0 = wS[base + k + half];
                float w1 = wS[base + k + 2 + half];
                float w2 = wS[base + k + 4 + half];
                float w3 = wS[base + k + 6 + half];
                unsigned r0 = *(const unsigned*)&featb[(size_t)s0 * DIM + 2 * hl];
                unsigned r1 = *(const unsigned*)&featb[(size_t)s1 * DIM + 2 * hl];
                unsigned r2 = *(const unsigned*)&featb[(size_t)s2 * DIM + 2 * hl];
                unsigned r3 = *(const unsigned*)&featb[(size_t)s3 * DIM + 2 * hl];
                ax += __uint_as_float(r0 << 16) * w0 + __uint_as_float(r1 << 16) * w1
                    + __uint_as_float(r2 << 16) * w2 + __uint_as_float(r3 << 16) * w3;
                ay += __uint_as_float(r0 & 0xFFFF0000u) * w0 + __uint_as_float(r1 & 0xFFFF0000u) * w1
                    + __uint_as_float(r2 & 0xFFFF0000u) * w2 + __uint_as_float(r3 & 0xFFFF0000u) * w3;
            }
            for (; k + 1 < deg; k += 2) {
                int s = srcS[base + k + half];
                float w = wS[base + k + half];
                unsigned r = *(const unsigned*)&featb[(size_t)s * DIM + 2 * hl];
                ax += __uint_as_float(r << 16) * w;
                ay += __uint_as_float(r & 0xFFFF0000u) * w;
            }
            if (k < deg && half == 0) {
                int s = srcS[base + k];
                float w = wS[base + k];
                unsigned r = *(const unsigned*)&featb[(size_t)s * DIM + 2 * hl];
                ax += __uint_as_float(r << 16) * w;
                ay += __uint_as_float(r & 0xFFFF0000u) * w;
            }
        }
        // Combine halves, store 256B coalesced from lanes 0..31.
        ax += __shfl_down(ax, 32);
        ay += __shfl_down(ay, 32);
        if (half == 0) {
            float* outp = (rel ? trans_out : out_geo) + (size_t)(node0 + nl) * DIM + 2 * hl;
            float2 o; o.x = ax; o.y = ay;
            *(float2*)outp = o;
        }
    }
    if (!rel && t < nNodes) cnt_out[node0 + t] = histS[t];
}

// ---------- W1 -> bf16, packed in B-fragment order ----------
__global__ void pack_w1_kernel(const float* __restrict__ W1, unsigned short* __restrict__ W1p) {
    int i = blockIdx.x * 256 + threadIdx.x;      // 0..16383
    int j = i & 7;
    int r = i >> 3;
    int nidx = r & 15; r >>= 4;
    int q = r & 3; r >>= 2;
    int khalf = r & 1;
    int n = r >> 1;
    int k = 32 * khalf + 8 * q + j;
    int c = 16 * n + nidx;
    W1p[i] = f2bf(W1[k * HID + c]);
}

// ---------- Semantic-attention MLP via bf16 MFMA ----------
__global__ void __launch_bounds__(256) mlp_mfma_kernel(
        const float* __restrict__ geo_raw, const float* __restrict__ trans,
        const int* __restrict__ cnt,
        const unsigned short* __restrict__ W1p,
        const float* __restrict__ bias1, const float* __restrict__ W2,
        float* __restrict__ partials) {
    __shared__ float wred[4][2];
    int t = threadIdx.x, lane = t & 63, wave = t >> 6;
    int m = lane & 15, q = lane >> 4;
    int base = blockIdx.x * 64 + wave * 16;
    int R = base + m;

    const float* rowp;
    float scale;
    if (R < N_NODES) {
        rowp = geo_raw + (size_t)R * DIM;
        scale = 1.0f / fmaxf((float)cnt[R], 1.0f);
    } else {
        rowp = trans + (size_t)(R - N_NODES) * DIM;
        scale = 1.0f;
    }

    float4 v0 = *(const float4*)(rowp + q * 8);
    float4 v1 = *(const float4*)(rowp + q * 8 + 4);
    float4 v2 = *(const float4*)(rowp + 32 + q * 8);
    float4 v3 = *(const float4*)(rowp + 32 + q * 8 + 4);
    short8 a0, a1;
    a0[0] = (short)f2bf(v0.x * scale); a0[1] = (short)f2bf(v0.y * scale);
    a0[2] = (short)f2bf(v0.z * scale); a0[3] = (short)f2bf(v0.w * scale);
    a0[4] = (short)f2bf(v1.x * scale); a0[5] = (short)f2bf(v1.y * scale);
    a0[6] = (short)f2bf(v1.z * scale); a0[7] = (short)f2bf(v1.w * scale);
    a1[0] = (short)f2bf(v2.x * scale); a1[1] = (short)f2bf(v2.y * scale);
    a1[2] = (short)f2bf(v2.z * scale); a1[3] = (short)f2bf(v2.w * scale);
    a1[4] = (short)f2bf(v3.x * scale); a1[5] = (short)f2bf(v3.y * scale);
    a1[6] = (short)f2bf(v3.z * scale); a1[7] = (short)f2bf(v3.w * scale);

    float c0 = 0.0f, c1 = 0.0f;
    const short8* W1v = (const short8*)W1p;   // 512 frags of 8 bf16

    #pragma unroll 4
    for (int n = 0; n < 16; ++n) {
        short8 b0 = W1v[(n * 2 + 0) * 64 + lane];
        short8 bK = W1v[(n * 2 + 1) * 64 + lane];
        f32x4 acc = {0.0f, 0.0f, 0.0f, 0.0f};
        acc = __builtin_amdgcn_mfma_f32_16x16x32_bf16(a0, b0, acc, 0, 0, 0);
        acc = __builtin_amdgcn_mfma_f32_16x16x32_bf16(a1, bK, acc, 0, 0, 0);
        int col = 16 * n + m;                 // C/D: col=lane&15, row=q*4+reg
        float bj = bias1[col];
        float w2 = W2[col];
        #pragma unroll
        for (int reg = 0; reg < 4; ++reg) {
            int Rr = base + q * 4 + reg;
            float h = tanh_fast(acc[reg] + bj);
            float contrib = h * w2;
            if (Rr < N_NODES) c0 += contrib; else c1 += contrib;
        }
    }

    #pragma unroll
    for (int off = 32; off > 0; off >>= 1) {
        c0 += __shfl_down(c0, off);
        c1 += __shfl_down(c1, off);
    }
    if (lane == 0) { wred[wave][0] = c0; wred[wave][1] = c1; }
    __syncthreads();
    if (t == 0) {
        partials[blockIdx.x * 2 + 0] = wred[0][0] + wred[1][0] + wred[2][0] + wred[3][0];
        partials[blockIdx.x * 2 + 1] = wred[0][1] + wred[1][1] + wred[2][1] + wred[3][1];
    }
}

__global__ void beta_kernel(const float* __restrict__ partials, float* __restrict__ beta) {
    __shared__ float wred[4][2];
    int t = threadIdx.x;
    float c0 = 0.0f, c1 = 0.0f;
    for (int i = t; i < MLP_ROWBLOCKS; i += 256) {
        c0 += partials[i * 2 + 0];
        c1 += partials[i * 2 + 1];
    }
    #pragma unroll
    for (int off = 32; off > 0; off >>= 1) {
        c0 += __shfl_down(c0, off);
        c1 += __shfl_down(c1, off);
    }
    int lane = t & 63, wv = t >> 6;
    if (lane == 0) { wred[wv][0] = c0; wred[wv][1] = c1; }
    __syncthreads();
    if (t == 0) {
        float s0 = (wred[0][0] + wred[1][0] + wred[2][0] + wred[3][0]) / (float)N_NODES;
        float s1 = (wred[0][1] + wred[1][1] + wred[2][1] + wred[3][1]) / (float)N_NODES;
        float m = fmaxf(s0, s1);
        float e0 = __expf(s0 - m), e1 = __expf(s1 - m);
        float inv = 1.0f / (e0 + e1);
        beta[0] = e0 * inv;
        beta[1] = e1 * inv;
    }
}

__global__ void combine_kernel(float* __restrict__ out_geo,
                               const float* __restrict__ trans,
                               const int* __restrict__ cnt,
                               const float* __restrict__ beta) {
    int gid = blockIdx.x * 256 + threadIdx.x;   // one float4 per thread
    int node = gid >> 4;
    float invc = 1.0f / fmaxf((float)cnt[node], 1.0f);
    float b0 = beta[0] * invc;
    float b1 = beta[1];
    float4 g = ((const float4*)out_geo)[gid];
    float4 tr = ((const float4*)trans)[gid];
    float4 o;
    o.x = b0 * g.x + b1 * tr.x;
    o.y = b0 * g.y + b1 * tr.y;
    o.z = b0 * g.z + b1 * tr.z;
    o.w = b0 * g.w + b1 * tr.w;
    ((float4*)out_geo)[gid] = o;
}

extern "C" void kernel_launch(void* const* d_in, const int* in_sizes, int n_in,
                              void* d_out, int out_size, void* d_ws, size_t ws_size,
                              hipStream_t stream) {
    const float* loc_feat = (const float*)d_in[0];
    const int* geo_src    = (const int*)d_in[1];
    const int* geo_dst    = (const int*)d_in[2];
    const int* trans_src  = (const int*)d_in[3];
    const int* trans_dst  = (const int*)d_in[4];
    const float* trans_w  = (const float*)d_in[5];
    const float* W1       = (const float*)d_in[6];
    const float* b1       = (const float*)d_in[7];
    const float* W2       = (const float*)d_in[8];
    float* out = (float*)d_out;

    // ws layout (4B units): [trans N*64][cnt N][gcount 2*NBINS][gbin NBINS*CAP]
    //   [tbin NBINS*CAP int2][partials 2*3125][beta 2][W1p 16384 u16][featb N*64 u16]
    // total ~54.3 MB
    float* trans    = (float*)d_ws;
    int*   cnt      = (int*)(trans + (size_t)N_NODES * DIM);
    int*   gcount   = cnt + N_NODES;
    int*   gbin     = gcount + 2 * NBINS;
    int2*  tbin     = (int2*)(gbin + (size_t)NBINS * CAP);
    float* partials = (float*)(tbin + (size_t)NBINS * CAP);
    float* beta     = partials + 2 * MLP_ROWBLOCKS;
    unsigned short* W1p   = (unsigned short*)(beta + 2);
    unsigned short* featb = W1p + 16384;

    hipMemsetAsync(gcount, 0, 2 * NBINS * sizeof(int), stream);

    pack_feat_kernel<<<(N_NODES * DIM / 4) / 256, 256, 0, stream>>>(loc_feat, featb);
    pack_w1_kernel<<<64, 256, 0, stream>>>(W1, W1p);
    bin_fill_kernel<<<2 * GEO_BLOCKS, 256, 0, stream>>>(geo_src, geo_dst, trans_src,
                                                        trans_dst, trans_w,
                                                        gcount, gbin, tbin);
    aggregate_kernel<<<2 * NBINS, 512, 0, stream>>>(featb, gbin, tbin, gcount,
                                                    out, trans, cnt);
    mlp_mfma_kernel<<<MLP_ROWBLOCKS, 256, 0, stream>>>(out, trans, cnt, W1p, b1, W2, partials);
    beta_kernel<<<1, 256, 0, stream>>>(partials, beta);
    combine_kernel<<<(N_NODES * DIM / 4) / 256, 256, 0, stream>>>(out, trans, cnt, beta);
}

// Round 7
// 247.687 us; speedup vs baseline: 4.2529x; 1.0175x over previous
//
#include <hip/hip_runtime.h>
#include <hip/hip_bf16.h>

// N=100000 nodes, D=64 feat, H=256 hidden, E=1000000 edges per relation.
#define N_NODES 100000
#define DIM 64
#define HID 256
#define E_EDGES 1000000
#define TWO_N (2 * N_NODES)
#define MLP_ROWBLOCKS (TWO_N / 64)                   // 3125 blocks of 64 z-rows

// Binned aggregation.
#define TILE 240                                     // nodes per bin
#define NBINS 417                                    // ceil(100000/240)
#define CAP 3072                                     // bin capacity; mean 2400, sd~49
#define EPB 8192                                     // edges per bin_fill block
#define GEO_BLOCKS 123                               // ceil(E/EPB)

typedef short short8 __attribute__((ext_vector_type(8)));   // 8 bf16 (4 VGPRs)
typedef float f32x4 __attribute__((ext_vector_type(4)));
typedef unsigned short us4 __attribute__((ext_vector_type(4)));

__device__ __forceinline__ float tanh_fast(float x) {
    x = fminf(fmaxf(x, -15.0f), 15.0f);
    float e = __expf(2.0f * x);
    return (e - 1.0f) / (e + 1.0f);
}

__device__ __forceinline__ unsigned short f2bf(float x) {   // RNE f32->bf16
    unsigned u = __float_as_uint(x);
    u = u + 0x7FFFu + ((u >> 16) & 1u);
    return (unsigned short)(u >> 16);
}

__device__ __forceinline__ float bf2f(unsigned short u) {
    return __uint_as_float(((unsigned)u) << 16);
}

// ---------- feat -> bf16 (gather working set 25.6 -> 12.8 MB) ----------
__global__ void pack_feat_kernel(const float* __restrict__ feat,
                                 unsigned short* __restrict__ fb) {
    int i = blockIdx.x * 256 + threadIdx.x;          // one float4 -> ushort4
    float4 v = ((const float4*)feat)[i];
    us4 o;
    o[0] = f2bf(v.x); o[1] = f2bf(v.y); o[2] = f2bf(v.z); o[3] = f2bf(v.w);
    ((us4*)fb)[i] = o;
}

// ---------- Phase A: bin edges by dst tile ----------
__global__ void bin_fill_kernel(const int* __restrict__ gs, const int* __restrict__ gd,
                                const int* __restrict__ ts, const int* __restrict__ td,
                                const float* __restrict__ tw,
                                int* __restrict__ gcount,
                                int* __restrict__ gbin, int2* __restrict__ tbin) {
    __shared__ int hist[NBINS];
    __shared__ int baseS[NBINS];
    __shared__ int cur[NBINS];
    int t = threadIdx.x;
    int blk = blockIdx.x;
    int rel = (blk >= GEO_BLOCKS) ? 1 : 0;
    int e0 = (rel ? blk - GEO_BLOCKS : blk) * EPB;
    const int* dstp = rel ? td : gd;
    const int* srcp = rel ? ts : gs;

    for (int i = t; i < NBINS; i += 256) { hist[i] = 0; cur[i] = 0; }
    __syncthreads();

    // Pass 1: histogram (int4 reads, 4 edges/thread/iter).
    #pragma unroll
    for (int j = 0; j < EPB / 1024; ++j) {
        int idx = e0 + j * 1024 + 4 * t;
        if (idx + 3 < E_EDGES) {
            int4 v = *(const int4*)&dstp[idx];
            atomicAdd(&hist[v.x / TILE], 1);
            atomicAdd(&hist[v.y / TILE], 1);
            atomicAdd(&hist[v.z / TILE], 1);
            atomicAdd(&hist[v.w / TILE], 1);
        } else {
            for (int i2 = 0; i2 < 4; ++i2)
                if (idx + i2 < E_EDGES) atomicAdd(&hist[dstp[idx + i2] / TILE], 1);
        }
    }
    __syncthreads();

    // Reserve global space: one device atomic per nonzero bin per block.
    for (int i = t; i < NBINS; i += 256) {
        int h = hist[i];
        baseS[i] = (h > 0) ? (i * CAP + atomicAdd(&gcount[rel * NBINS + i], h)) : 0;
    }
    __syncthreads();

    // Pass 2: fill (dst re-read is L2-hot).
    if (!rel) {
        #pragma unroll
        for (int j = 0; j < EPB / 1024; ++j) {
            int idx = e0 + j * 1024 + 4 * t;
            bool vec = (idx + 3 < E_EDGES);
            int4 dv, sv;
            if (vec) { dv = *(const int4*)&dstp[idx]; sv = *(const int4*)&srcp[idx]; }
            int dd[4] = {dv.x, dv.y, dv.z, dv.w};
            int ss[4] = {sv.x, sv.y, sv.z, sv.w};
            for (int i2 = 0; i2 < 4; ++i2) {
                if (!vec) {
                    if (idx + i2 >= E_EDGES) continue;
                    dd[i2] = dstp[idx + i2]; ss[i2] = srcp[idx + i2];
                }
                int d = dd[i2];
                int bin = d / TILE;
                int pos = atomicAdd(&cur[bin], 1);
                int gi = baseS[bin] + pos;
                if (gi < (bin + 1) * CAP)                       // overflow guard (P~0)
                    gbin[gi] = ss[i2] | ((d - bin * TILE) << 20);
            }
        }
    } else {
        #pragma unroll
        for (int j = 0; j < EPB / 1024; ++j) {
            int idx = e0 + j * 1024 + 4 * t;
            bool vec = (idx + 3 < E_EDGES);
            int4 dv, sv; float4 wv;
            if (vec) {
                dv = *(const int4*)&dstp[idx];
                sv = *(const int4*)&srcp[idx];
                wv = *(const float4*)&tw[idx];
            }
            int dd[4] = {dv.x, dv.y, dv.z, dv.w};
            int ss[4] = {sv.x, sv.y, sv.z, sv.w};
            float ww[4] = {wv.x, wv.y, wv.z, wv.w};
            for (int i2 = 0; i2 < 4; ++i2) {
                if (!vec) {
                    if (idx + i2 >= E_EDGES) continue;
                    dd[i2] = dstp[idx + i2]; ss[i2] = srcp[idx + i2]; ww[i2] = tw[idx + i2];
                }
                int d = dd[i2];
                int bin = d / TILE;
                int pos = atomicAdd(&cur[bin], 1);
                int gi = baseS[bin] + pos;
                if (gi < (bin + 1) * CAP)
                    tbin[gi] = make_int2(ss[i2] | ((d - bin * TILE) << 20),
                                         __float_as_int(ww[i2]));
            }
        }
    }
}

// ---------- Phase B: LDS counting sort + quarter-wave gather; bf16 z output ----------
// zb rows 0..N-1 = geo MEAN (pre-divided by deg); rows N..2N-1 = trans weighted sum.
__global__ void __launch_bounds__(512) aggregate_kernel(
        const unsigned short* __restrict__ featb,
        const int* __restrict__ gbin, const int2* __restrict__ tbin,
        const int* __restrict__ gcount,
        unsigned short* __restrict__ zb) {
    __shared__ int   srcS[CAP];      // 12 KB  sorted src ids
    __shared__ float wS[CAP];        // 12 KB  sorted weights (trans only)
    __shared__ int   histS[TILE];
    __shared__ int   baseS[TILE];
    __shared__ int   curS[TILE];
    __shared__ int   scanS[256];

    int b = blockIdx.x;
    int rel = (b >= NBINS) ? 1 : 0;
    int bin = rel ? b - NBINS : b;
    int node0 = bin * TILE;
    int nNodes = min(TILE, N_NODES - node0);
    int t = threadIdx.x, lane = t & 63, wave = t >> 6;
    int q = lane >> 4, ql = lane & 15;               // quarter id / lane-in-quarter

    int nE = gcount[b];
    if (nE > CAP) nE = CAP;

    for (int i = t; i < TILE; i += 512) histS[i] = 0;
    __syncthreads();

    // Pass 1: histogram over local dst (scalar LDS atomics).
    if (!rel) {
        const int* bp = gbin + (size_t)bin * CAP;
        for (int i = t; i < nE; i += 512) atomicAdd(&histS[bp[i] >> 20], 1);
    } else {
        const int2* bp = tbin + (size_t)bin * CAP;
        for (int i = t; i < nE; i += 512) atomicAdd(&histS[bp[i].x >> 20], 1);
    }
    __syncthreads();

    // Exclusive scan of histS.
    if (t < 256) scanS[t] = (t < TILE) ? histS[t] : 0;
    __syncthreads();
    #pragma unroll
    for (int off = 1; off < 256; off <<= 1) {
        int add = 0;
        if (t < 256 && t >= off) add = scanS[t - off];
        __syncthreads();
        if (t < 256) scanS[t] += add;
        __syncthreads();
    }
    if (t < TILE) {
        int base = scanS[t] - histS[t];
        baseS[t] = base;
        curS[t] = base;
    }
    __syncthreads();

    // Pass 2: place payload into sorted LDS lists.
    if (!rel) {
        const int* bp = gbin + (size_t)bin * CAP;
        for (int i = t; i < nE; i += 512) {
            int p = bp[i];
            int pos = atomicAdd(&curS[p >> 20], 1);
            srcS[pos] = p & 0xFFFFF;
        }
    } else {
        const int2* bp = tbin + (size_t)bin * CAP;
        for (int i = t; i < nE; i += 512) {
            int2 p = bp[i];
            int pos = atomicAdd(&curS[p.x >> 20], 1);
            srcS[pos] = p.x & 0xFFFFF;
            wS[pos] = __int_as_float(p.y);
        }
    }
    __syncthreads();

    // Pass 3: wave-per-node; quarter q handles edge k+q; lane loads ushort4 (8B)
    // covering dims [ql*4, ql*4+4). 4 edges per load instruction, unroll-2.
    for (int nl = wave; nl < nNodes; nl += 8) {
        int deg = histS[nl];
        int base = baseS[nl];
        float a0 = 0.f, a1 = 0.f, a2 = 0.f, a3 = 0.f;
        if (!rel) {
            int k = 0;
            for (; k + 7 < deg; k += 8) {
                int s0 = srcS[base + k + q];
                int s1 = srcS[base + k + 4 + q];
                us4 r0 = *(const us4*)&featb[(size_t)s0 * DIM + ql * 4];
                us4 r1 = *(const us4*)&featb[(size_t)s1 * DIM + ql * 4];
                a0 += bf2f(r0[0]) + bf2f(r1[0]);
                a1 += bf2f(r0[1]) + bf2f(r1[1]);
                a2 += bf2f(r0[2]) + bf2f(r1[2]);
                a3 += bf2f(r0[3]) + bf2f(r1[3]);
            }
            for (; k < deg; k += 4) {
                int e = k + q;
                if (e < deg) {
                    int s = srcS[base + e];
                    us4 r = *(const us4*)&featb[(size_t)s * DIM + ql * 4];
                    a0 += bf2f(r[0]); a1 += bf2f(r[1]);
                    a2 += bf2f(r[2]); a3 += bf2f(r[3]);
                }
            }
        } else {
            int k = 0;
            for (; k + 7 < deg; k += 8) {
                int s0 = srcS[base + k + q];
                int s1 = srcS[base + k + 4 + q];
                float w0 = wS[base + k + q];
                float w1 = wS[base + k + 4 + q];
                us4 r0 = *(const us4*)&featb[(size_t)s0 * DIM + ql * 4];
                us4 r1 = *(const us4*)&featb[(size_t)s1 * DIM + ql * 4];
                a0 += bf2f(r0[0]) * w0 + bf2f(r1[0]) * w1;
                a1 += bf2f(r0[1]) * w0 + bf2f(r1[1]) * w1;
                a2 += bf2f(r0[2]) * w0 + bf2f(r1[2]) * w1;
                a3 += bf2f(r0[3]) * w0 + bf2f(r1[3]) * w1;
            }
            for (; k < deg; k += 4) {
                int e = k + q;
                if (e < deg) {
                    int s = srcS[base + e];
                    float w = wS[base + e];
                    us4 r = *(const us4*)&featb[(size_t)s * DIM + ql * 4];
                    a0 += bf2f(r[0]) * w; a1 += bf2f(r[1]) * w;
                    a2 += bf2f(r[2]) * w; a3 += bf2f(r[3]) * w;
                }
            }
        }
        // Reduce across quarters (lane += lane+16, then lane+32).
        a0 += __shfl_down(a0, 16); a1 += __shfl_down(a1, 16);
        a2 += __shfl_down(a2, 16); a3 += __shfl_down(a3, 16);
        a0 += __shfl_down(a0, 32); a1 += __shfl_down(a1, 32);
        a2 += __shfl_down(a2, 32); a3 += __shfl_down(a3, 32);
        if (lane < 16) {
            float sc = rel ? 1.0f : 1.0f / fmaxf((float)deg, 1.0f);   // geo -> mean
            us4 o;
            o[0] = f2bf(a0 * sc); o[1] = f2bf(a1 * sc);
            o[2] = f2bf(a2 * sc); o[3] = f2bf(a3 * sc);
            size_t row = (size_t)(rel ? N_NODES + node0 + nl : node0 + nl);
            *(us4*)&zb[row * DIM + ql * 4] = o;
        }
    }
}

// ---------- W1 -> bf16, packed in B-fragment order ----------
__global__ void pack_w1_kernel(const float* __restrict__ W1, unsigned short* __restrict__ W1p) {
    int i = blockIdx.x * 256 + threadIdx.x;      // 0..16383
    int j = i & 7;
    int r = i >> 3;
    int nidx = r & 15; r >>= 4;
    int q = r & 3; r >>= 2;
    int khalf = r & 1;
    int n = r >> 1;
    int k = 32 * khalf + 8 * q + j;
    int c = 16 * n + nidx;
    W1p[i] = f2bf(W1[k * HID + c]);
}

// ---------- Semantic-attention MLP via bf16 MFMA; A-frags loaded directly from zb ----
__global__ void __launch_bounds__(256) mlp_mfma_kernel(
        const unsigned short* __restrict__ zb,
        const unsigned short* __restrict__ W1p,
        const float* __restrict__ bias1, const float* __restrict__ W2,
        float* __restrict__ partials) {
    __shared__ float wred[4][2];
    int t = threadIdx.x, lane = t & 63, wave = t >> 6;
    int m = lane & 15, q = lane >> 4;
    int base = blockIdx.x * 64 + wave * 16;
    int R = base + m;

    const unsigned short* rowp = zb + (size_t)R * DIM;
    short8 a0 = *(const short8*)(rowp + q * 8);          // k = q*8..q*8+7
    short8 a1 = *(const short8*)(rowp + 32 + q * 8);     // k = 32+q*8..

    float c0 = 0.0f, c1 = 0.0f;
    const short8* W1v = (const short8*)W1p;   // 512 frags of 8 bf16

    #pragma unroll 4
    for (int n = 0; n < 16; ++n) {
        short8 b0 = W1v[(n * 2 + 0) * 64 + lane];
        short8 bK = W1v[(n * 2 + 1) * 64 + lane];
        f32x4 acc = {0.0f, 0.0f, 0.0f, 0.0f};
        acc = __builtin_amdgcn_mfma_f32_16x16x32_bf16(a0, b0, acc, 0, 0, 0);
        acc = __builtin_amdgcn_mfma_f32_16x16x32_bf16(a1, bK, acc, 0, 0, 0);
        int col = 16 * n + m;                 // C/D: col=lane&15, row=q*4+reg
        float bj = bias1[col];
        float w2 = W2[col];
        #pragma unroll
        for (int reg = 0; reg < 4; ++reg) {
            int Rr = base + q * 4 + reg;
            float h = tanh_fast(acc[reg] + bj);
            float contrib = h * w2;
            if (Rr < N_NODES) c0 += contrib; else c1 += contrib;
        }
    }

    #pragma unroll
    for (int off = 32; off > 0; off >>= 1) {
        c0 += __shfl_down(c0, off);
        c1 += __shfl_down(c1, off);
    }
    if (lane == 0) { wred[wave][0] = c0; wred[wave][1] = c1; }
    __syncthreads();
    if (t == 0) {
        partials[blockIdx.x * 2 + 0] = wred[0][0] + wred[1][0] + wred[2][0] + wred[3][0];
        partials[blockIdx.x * 2 + 1] = wred[0][1] + wred[1][1] + wred[2][1] + wred[3][1];
    }
}

__global__ void beta_kernel(const float* __restrict__ partials, float* __restrict__ beta) {
    __shared__ float wred[4][2];
    int t = threadIdx.x;
    float c0 = 0.0f, c1 = 0.0f;
    for (int i = t; i < MLP_ROWBLOCKS; i += 256) {
        c0 += partials[i * 2 + 0];
        c1 += partials[i * 2 + 1];
    }
    #pragma unroll
    for (int off = 32; off > 0; off >>= 1) {
        c0 += __shfl_down(c0, off);
        c1 += __shfl_down(c1, off);
    }
    int lane = t & 63, wv = t >> 6;
    if (lane == 0) { wred[wv][0] = c0; wred[wv][1] = c1; }
    __syncthreads();
    if (t == 0) {
        float s0 = (wred[0][0] + wred[1][0] + wred[2][0] + wred[3][0]) / (float)N_NODES;
        float s1 = (wred[0][1] + wred[1][1] + wred[2][1] + wred[3][1]) / (float)N_NODES;
        float m = fmaxf(s0, s1);
        float e0 = __expf(s0 - m), e1 = __expf(s1 - m);
        float inv = 1.0f / (e0 + e1);
        beta[0] = e0 * inv;
        beta[1] = e1 * inv;
    }
}

// out = beta0 * geo_mean + beta1 * trans, reading bf16 z.
__global__ void combine_kernel(const unsigned short* __restrict__ zb,
                               const float* __restrict__ beta,
                               float* __restrict__ out) {
    int gid = blockIdx.x * 256 + threadIdx.x;   // 8 elements per thread
    float b0 = beta[0];
    float b1 = beta[1];
    uint4 g = *(const uint4*)&zb[(size_t)gid * 8];
    uint4 tr = *(const uint4*)&zb[(size_t)N_NODES * DIM + (size_t)gid * 8];
    float4 o0, o1;
    o0.x = b0 * __uint_as_float(g.x << 16) + b1 * __uint_as_float(tr.x << 16);
    o0.y = b0 * __uint_as_float(g.x & 0xFFFF0000u) + b1 * __uint_as_float(tr.x & 0xFFFF0000u);
    o0.z = b0 * __uint_as_float(g.y << 16) + b1 * __uint_as_float(tr.y << 16);
    o0.w = b0 * __uint_as_float(g.y & 0xFFFF0000u) + b1 * __uint_as_float(tr.y & 0xFFFF0000u);
    o1.x = b0 * __uint_as_float(g.z << 16) + b1 * __uint_as_float(tr.z << 16);
    o1.y = b0 * __uint_as_float(g.z & 0xFFFF0000u) + b1 * __uint_as_float(tr.z & 0xFFFF0000u);
    o1.z = b0 * __uint_as_float(g.w << 16) + b1 * __uint_as_float(tr.w << 16);
    o1.w = b0 * __uint_as_float(g.w & 0xFFFF0000u) + b1 * __uint_as_float(tr.w & 0xFFFF0000u);
    *(float4*)&out[(size_t)gid * 8] = o0;
    *(float4*)&out[(size_t)gid * 8 + 4] = o1;
}

extern "C" void kernel_launch(void* const* d_in, const int* in_sizes, int n_in,
                              void* d_out, int out_size, void* d_ws, size_t ws_size,
                              hipStream_t stream) {
    const float* loc_feat = (const float*)d_in[0];
    const int* geo_src    = (const int*)d_in[1];
    const int* geo_dst    = (const int*)d_in[2];
    const int* trans_src  = (const int*)d_in[3];
    const int* trans_dst  = (const int*)d_in[4];
    const float* trans_w  = (const float*)d_in[5];
    const float* W1       = (const float*)d_in[6];
    const float* b1       = (const float*)d_in[7];
    const float* W2       = (const float*)d_in[8];
    float* out = (float*)d_out;

    // ws layout (4B units): [gcount 2*NBINS][gbin NBINS*CAP int][tbin NBINS*CAP int2]
    //   [partials 2*3125][beta 2][W1p 16384 u16][featb N*64 u16][zb 2N*64 u16]  ~54 MB
    int*   gcount   = (int*)d_ws;
    int*   gbin     = gcount + 2 * NBINS;
    int2*  tbin     = (int2*)(gbin + (size_t)NBINS * CAP);
    float* partials = (float*)(tbin + (size_t)NBINS * CAP);
    float* beta     = partials + 2 * MLP_ROWBLOCKS;
    unsigned short* W1p   = (unsigned short*)(beta + 2);
    unsigned short* featb = W1p + 16384;
    unsigned short* zb    = featb + (size_t)N_NODES * DIM;

    hipMemsetAsync(gcount, 0, 2 * NBINS * sizeof(int), stream);

    pack_feat_kernel<<<(N_NODES * DIM / 4) / 256, 256, 0, stream>>>(loc_feat, featb);
    pack_w1_kernel<<<64, 256, 0, stream>>>(W1, W1p);
    bin_fill_kernel<<<2 * GEO_BLOCKS, 256, 0, stream>>>(geo_src, geo_dst, trans_src,
                                                        trans_dst, trans_w,
                                                        gcount, gbin, tbin);
    aggregate_kernel<<<2 * NBINS, 512, 0, stream>>>(featb, gbin, tbin, gcount, zb);
    mlp_mfma_kernel<<<MLP_ROWBLOCKS, 256, 0, stream>>>(zb, W1p, b1, W2, partials);
    beta_kernel<<<1, 256, 0, stream>>>(partials, beta);
    combine_kernel<<<(N_NODES * DIM / 8) / 256, 256, 0, stream>>>(zb, beta, out);
}

// Round 8
// 233.917 us; speedup vs baseline: 4.5032x; 1.0589x over previous
//
#include <hip/hip_runtime.h>
#include <hip/hip_bf16.h>

// N=100000 nodes, D=64 feat, H=256 hidden, E=1000000 edges per relation.
#define N_NODES 100000
#define DIM 64
#define HID 256
#define E_EDGES 1000000
#define TWO_N (2 * N_NODES)
#define MLP_ROWBLOCKS (TWO_N / 64)                   // 3125 blocks of 64 z-rows

// Binned aggregation.
#define TILE 120                                     // nodes per bin
#define NBINS 834                                    // ceil(100000/120)
#define CAP 1600                                     // mean 1200, sd ~35 -> +11.6 sd
#define EPB 4096                                     // edges per bin_fill block
#define FILL_BLOCKS 245                              // ceil(E/EPB)

typedef short short8 __attribute__((ext_vector_type(8)));   // 8 bf16 (4 VGPRs)
typedef float f32x4 __attribute__((ext_vector_type(4)));
typedef unsigned short us4 __attribute__((ext_vector_type(4)));

__device__ __forceinline__ float tanh_fast(float x) {
    x = fminf(fmaxf(x, -15.0f), 15.0f);
    float e = __expf(2.0f * x);
    return (e - 1.0f) / (e + 1.0f);
}

__device__ __forceinline__ unsigned short f2bf(float x) {   // RNE f32->bf16
    unsigned u = __float_as_uint(x);
    u = u + 0x7FFFu + ((u >> 16) & 1u);
    return (unsigned short)(u >> 16);
}

__device__ __forceinline__ float bf2f(unsigned short u) {
    return __uint_as_float(((unsigned)u) << 16);
}

// ---------- feat -> bf16 (gather working set 25.6 -> 12.8 MB) ----------
__global__ void pack_feat_kernel(const float* __restrict__ feat,
                                 unsigned short* __restrict__ fb) {
    int i = blockIdx.x * 256 + threadIdx.x;          // one float4 -> ushort4
    float4 v = ((const float4*)feat)[i];
    us4 o;
    o[0] = f2bf(v.x); o[1] = f2bf(v.y); o[2] = f2bf(v.z); o[3] = f2bf(v.w);
    ((us4*)fb)[i] = o;
}

// ---------- Phase A: block-local counting sort by bin + coalesced copy-out ----------
__global__ void __launch_bounds__(512) bin_fill_kernel(
        const int* __restrict__ gs, const int* __restrict__ gd,
        const int* __restrict__ ts, const int* __restrict__ td,
        const float* __restrict__ tw,
        int* __restrict__ gcount,
        int* __restrict__ gbin, int2* __restrict__ tbin) {
    __shared__ int   hist[NBINS];
    __shared__ int   adjS[NBINS];                    // gbase - lbase per bin
    __shared__ int   curS[NBINS];
    __shared__ int   pS[EPB];                        // sorted payload (src|dloc<<20)
    __shared__ float w2S[EPB];                       // sorted weights (trans only)
    __shared__ unsigned short binS[EPB];             // bin of sorted slot
    __shared__ int   scanS[512];

    int t = threadIdx.x;
    int blk = blockIdx.x;
    int rel = (blk >= FILL_BLOCKS) ? 1 : 0;
    int e0 = (rel ? blk - FILL_BLOCKS : blk) * EPB;
    const int* dstp = rel ? td : gd;
    const int* srcp = rel ? ts : gs;

    for (int i = t; i < NBINS; i += 512) hist[i] = 0;
    __syncthreads();

    // Load 8 edges per thread into registers (int4 reads), histogram.
    int d_[8], s_[8];
    float w_[8];
    #pragma unroll
    for (int j = 0; j < 2; ++j) {
        int idx = e0 + j * 2048 + 4 * t;
        if (idx + 3 < E_EDGES) {
            int4 dv = *(const int4*)&dstp[idx];
            int4 sv = *(const int4*)&srcp[idx];
            d_[4*j+0] = dv.x; d_[4*j+1] = dv.y; d_[4*j+2] = dv.z; d_[4*j+3] = dv.w;
            s_[4*j+0] = sv.x; s_[4*j+1] = sv.y; s_[4*j+2] = sv.z; s_[4*j+3] = sv.w;
            if (rel) {
                float4 wv = *(const float4*)&tw[idx];
                w_[4*j+0] = wv.x; w_[4*j+1] = wv.y; w_[4*j+2] = wv.z; w_[4*j+3] = wv.w;
            }
        } else {
            #pragma unroll
            for (int i2 = 0; i2 < 4; ++i2) {
                bool ok = (idx + i2 < E_EDGES);
                d_[4*j+i2] = ok ? dstp[idx + i2] : -1;
                s_[4*j+i2] = ok ? srcp[idx + i2] : 0;
                w_[4*j+i2] = (ok && rel) ? tw[idx + i2] : 0.0f;
            }
        }
    }
    #pragma unroll
    for (int i = 0; i < 8; ++i)
        if (d_[i] >= 0) atomicAdd(&hist[d_[i] / TILE], 1);
    __syncthreads();

    // Exclusive scan over NBINS (512-chunks with carry); reserve global space.
    int carry = 0;
    for (int cb = 0; cb < NBINS; cb += 512) {
        int i = cb + t;
        int c = (i < NBINS) ? hist[i] : 0;
        __syncthreads();
        scanS[t] = c;
        __syncthreads();
        int v = c;
        #pragma unroll
        for (int off = 1; off < 512; off <<= 1) {
            int add = (t >= off) ? scanS[t - off] : 0;
            __syncthreads();
            v += add;
            scanS[t] = v;
            __syncthreads();
        }
        if (i < NBINS) {
            int lb = v - c + carry;
            curS[i] = lb;
            int gb = (c > 0) ? (i * CAP + atomicAdd(&gcount[rel * NBINS + i], c)) : 0;
            adjS[i] = gb - lb;
        }
        carry += scanS[511];
    }
    __syncthreads();

    // Place into sorted LDS order.
    #pragma unroll
    for (int i = 0; i < 8; ++i) {
        int d = d_[i];
        if (d < 0) continue;
        int bin = d / TILE;
        int pos = atomicAdd(&curS[bin], 1);
        pS[pos] = s_[i] | ((d - bin * TILE) << 20);
        binS[pos] = (unsigned short)bin;
        if (rel) w2S[pos] = w_[i];
    }
    __syncthreads();

    // Coalesced copy-out: consecutive slots in a bin -> consecutive global addrs.
    int nV = min(EPB, E_EDGES - e0);
    if (!rel) {
        for (int i = t; i < nV; i += 512) {
            int b = binS[i];
            int gi = adjS[b] + i;
            if (gi < (b + 1) * CAP)                          // overflow guard (P~0)
                gbin[gi] = pS[i];
        }
    } else {
        for (int i = t; i < nV; i += 512) {
            int b = binS[i];
            int gi = adjS[b] + i;
            if (gi < (b + 1) * CAP)
                tbin[gi] = make_int2(pS[i], __float_as_int(w2S[i]));
        }
    }
}

// ---------- Phase B: LDS counting sort + quarter-wave-per-node gather ----------
// zb rows 0..N-1 = geo MEAN; rows N..2N-1 = trans weighted sum. bf16 output.
__global__ void __launch_bounds__(256) aggregate_kernel(
        const unsigned short* __restrict__ featb,
        const int* __restrict__ gbin, const int2* __restrict__ tbin,
        const int* __restrict__ gcount,
        unsigned short* __restrict__ zb) {
    __shared__ int   srcS[CAP];      // 6.4 KB sorted src ids
    __shared__ float wS[CAP];        // 6.4 KB sorted weights (trans only)
    __shared__ int   histS[TILE];
    __shared__ int   baseS[TILE];
    __shared__ int   curS[TILE];
    __shared__ int   scanS[128];

    int b = blockIdx.x;
    int rel = (b >= NBINS) ? 1 : 0;
    int bin = rel ? b - NBINS : b;
    int node0 = bin * TILE;
    int nNodes = min(TILE, N_NODES - node0);
    int t = threadIdx.x, lane = t & 63, wave = t >> 6;   // 4 waves
    int q = lane >> 4, ql = lane & 15;                   // quarter / lane-in-quarter

    int nE = gcount[b];
    if (nE > CAP) nE = CAP;

    for (int i = t; i < TILE; i += 256) histS[i] = 0;
    __syncthreads();

    // Pass 1: histogram over local dst.
    if (!rel) {
        const int* bp = gbin + (size_t)bin * CAP;
        for (int i = t; i < nE; i += 256) atomicAdd(&histS[bp[i] >> 20], 1);
    } else {
        const int2* bp = tbin + (size_t)bin * CAP;
        for (int i = t; i < nE; i += 256) atomicAdd(&histS[bp[i].x >> 20], 1);
    }
    __syncthreads();

    // Exclusive scan (TILE=120 <= 128 lanes).
    if (t < 128) scanS[t] = (t < TILE) ? histS[t] : 0;
    __syncthreads();
    #pragma unroll
    for (int off = 1; off < 128; off <<= 1) {
        int add = 0;
        if (t < 128 && t >= off) add = scanS[t - off];
        __syncthreads();
        if (t < 128) scanS[t] += add;
        __syncthreads();
    }
    if (t < TILE) {
        int base = scanS[t] - histS[t];
        baseS[t] = base;
        curS[t] = base;
    }
    __syncthreads();

    // Pass 2: place payload into sorted LDS lists.
    if (!rel) {
        const int* bp = gbin + (size_t)bin * CAP;
        for (int i = t; i < nE; i += 256) {
            int p = bp[i];
            int pos = atomicAdd(&curS[p >> 20], 1);
            srcS[pos] = p & 0xFFFFF;
        }
    } else {
        const int2* bp = tbin + (size_t)bin * CAP;
        for (int i = t; i < nE; i += 256) {
            int2 p = bp[i];
            int pos = atomicAdd(&curS[p.x >> 20], 1);
            srcS[pos] = p.x & 0xFFFFF;
            wS[pos] = __int_as_float(p.y);
        }
    }
    __syncthreads();

    // Pass 3: quarter q owns node nl0+q entirely (full row, 16 lanes x 8B = 128B).
    // unroll-4 -> 4 independent row loads in flight per quarter; no shuffles.
    for (int nl0 = wave * 4; nl0 < nNodes; nl0 += 16) {
        int nl = nl0 + q;
        bool act = (nl < nNodes);
        int deg = act ? histS[nl] : 0;
        int base = act ? baseS[nl] : 0;
        float a0 = 0.f, a1 = 0.f, a2 = 0.f, a3 = 0.f;
        if (!rel) {
            int k = 0;
            for (; k + 3 < deg; k += 4) {
                int s0 = srcS[base + k], s1 = srcS[base + k + 1];
                int s2 = srcS[base + k + 2], s3 = srcS[base + k + 3];
                us4 r0 = *(const us4*)&featb[(size_t)s0 * DIM + ql * 4];
                us4 r1 = *(const us4*)&featb[(size_t)s1 * DIM + ql * 4];
                us4 r2 = *(const us4*)&featb[(size_t)s2 * DIM + ql * 4];
                us4 r3 = *(const us4*)&featb[(size_t)s3 * DIM + ql * 4];
                a0 += (bf2f(r0[0]) + bf2f(r1[0])) + (bf2f(r2[0]) + bf2f(r3[0]));
                a1 += (bf2f(r0[1]) + bf2f(r1[1])) + (bf2f(r2[1]) + bf2f(r3[1]));
                a2 += (bf2f(r0[2]) + bf2f(r1[2])) + (bf2f(r2[2]) + bf2f(r3[2]));
                a3 += (bf2f(r0[3]) + bf2f(r1[3])) + (bf2f(r2[3]) + bf2f(r3[3]));
            }
            for (; k < deg; ++k) {
                int s = srcS[base + k];
                us4 r = *(const us4*)&featb[(size_t)s * DIM + ql * 4];
                a0 += bf2f(r[0]); a1 += bf2f(r[1]);
                a2 += bf2f(r[2]); a3 += bf2f(r[3]);
            }
        } else {
            int k = 0;
            for (; k + 3 < deg; k += 4) {
                int s0 = srcS[base + k], s1 = srcS[base + k + 1];
                int s2 = srcS[base + k + 2], s3 = srcS[base + k + 3];
                float w0 = wS[base + k], w1 = wS[base + k + 1];
                float w2 = wS[base + k + 2], w3 = wS[base + k + 3];
                us4 r0 = *(const us4*)&featb[(size_t)s0 * DIM + ql * 4];
                us4 r1 = *(const us4*)&featb[(size_t)s1 * DIM + ql * 4];
                us4 r2 = *(const us4*)&featb[(size_t)s2 * DIM + ql * 4];
                us4 r3 = *(const us4*)&featb[(size_t)s3 * DIM + ql * 4];
                a0 += (bf2f(r0[0]) * w0 + bf2f(r1[0]) * w1) + (bf2f(r2[0]) * w2 + bf2f(r3[0]) * w3);
                a1 += (bf2f(r0[1]) * w0 + bf2f(r1[1]) * w1) + (bf2f(r2[1]) * w2 + bf2f(r3[1]) * w3);
                a2 += (bf2f(r0[2]) * w0 + bf2f(r1[2]) * w1) + (bf2f(r2[2]) * w2 + bf2f(r3[2]) * w3);
                a3 += (bf2f(r0[3]) * w0 + bf2f(r1[3]) * w1) + (bf2f(r2[3]) * w2 + bf2f(r3[3]) * w3);
            }
            for (; k < deg; ++k) {
                int s = srcS[base + k];
                float w = wS[base + k];
                us4 r = *(const us4*)&featb[(size_t)s * DIM + ql * 4];
                a0 += bf2f(r[0]) * w; a1 += bf2f(r[1]) * w;
                a2 += bf2f(r[2]) * w; a3 += bf2f(r[3]) * w;
            }
        }
        if (act) {
            float sc = rel ? 1.0f : 1.0f / fmaxf((float)deg, 1.0f);   // geo -> mean
            us4 o;
            o[0] = f2bf(a0 * sc); o[1] = f2bf(a1 * sc);
            o[2] = f2bf(a2 * sc); o[3] = f2bf(a3 * sc);
            size_t row = (size_t)(rel ? N_NODES + node0 + nl : node0 + nl);
            *(us4*)&zb[row * DIM + ql * 4] = o;
        }
    }
}

// ---------- W1 -> bf16, packed in B-fragment order ----------
__global__ void pack_w1_kernel(const float* __restrict__ W1, unsigned short* __restrict__ W1p) {
    int i = blockIdx.x * 256 + threadIdx.x;      // 0..16383
    int j = i & 7;
    int r = i >> 3;
    int nidx = r & 15; r >>= 4;
    int q = r & 3; r >>= 2;
    int khalf = r & 1;
    int n = r >> 1;
    int k = 32 * khalf + 8 * q + j;
    int c = 16 * n + nidx;
    W1p[i] = f2bf(W1[k * HID + c]);
}

// ---------- Semantic-attention MLP via bf16 MFMA; A-frags loaded directly from zb ----
__global__ void __launch_bounds__(256) mlp_mfma_kernel(
        const unsigned short* __restrict__ zb,
        const unsigned short* __restrict__ W1p,
        const float* __restrict__ bias1, const float* __restrict__ W2,
        float* __restrict__ partials) {
    __shared__ float wred[4][2];
    int t = threadIdx.x, lane = t & 63, wave = t >> 6;
    int m = lane & 15, q = lane >> 4;
    int base = blockIdx.x * 64 + wave * 16;
    int R = base + m;

    const unsigned short* rowp = zb + (size_t)R * DIM;
    short8 a0 = *(const short8*)(rowp + q * 8);          // k = q*8..q*8+7
    short8 a1 = *(const short8*)(rowp + 32 + q * 8);     // k = 32+q*8..

    float c0 = 0.0f, c1 = 0.0f;
    const short8* W1v = (const short8*)W1p;   // 512 frags of 8 bf16

    #pragma unroll 4
    for (int n = 0; n < 16; ++n) {
        short8 b0 = W1v[(n * 2 + 0) * 64 + lane];
        short8 bK = W1v[(n * 2 + 1) * 64 + lane];
        f32x4 acc = {0.0f, 0.0f, 0.0f, 0.0f};
        acc = __builtin_amdgcn_mfma_f32_16x16x32_bf16(a0, b0, acc, 0, 0, 0);
        acc = __builtin_amdgcn_mfma_f32_16x16x32_bf16(a1, bK, acc, 0, 0, 0);
        int col = 16 * n + m;                 // C/D: col=lane&15, row=q*4+reg
        float bj = bias1[col];
        float w2 = W2[col];
        #pragma unroll
        for (int reg = 0; reg < 4; ++reg) {
            int Rr = base + q * 4 + reg;
            float h = tanh_fast(acc[reg] + bj);
            float contrib = h * w2;
            if (Rr < N_NODES) c0 += contrib; else c1 += contrib;
        }
    }

    #pragma unroll
    for (int off = 32; off > 0; off >>= 1) {
        c0 += __shfl_down(c0, off);
        c1 += __shfl_down(c1, off);
    }
    if (lane == 0) { wred[wave][0] = c0; wred[wave][1] = c1; }
    __syncthreads();
    if (t == 0) {
        partials[blockIdx.x * 2 + 0] = wred[0][0] + wred[1][0] + wred[2][0] + wred[3][0];
        partials[blockIdx.x * 2 + 1] = wred[0][1] + wred[1][1] + wred[2][1] + wred[3][1];
    }
}

__global__ void beta_kernel(const float* __restrict__ partials, float* __restrict__ beta) {
    __shared__ float wred[4][2];
    int t = threadIdx.x;
    float c0 = 0.0f, c1 = 0.0f;
    for (int i = t; i < MLP_ROWBLOCKS; i += 256) {
        c0 += partials[i * 2 + 0];
        c1 += partials[i * 2 + 1];
    }
    #pragma unroll
    for (int off = 32; off > 0; off >>= 1) {
        c0 += __shfl_down(c0, off);
        c1 += __shfl_down(c1, off);
    }
    int lane = t & 63, wv = t >> 6;
    if (lane == 0) { wred[wv][0] = c0; wred[wv][1] = c1; }
    __syncthreads();
    if (t == 0) {
        float s0 = (wred[0][0] + wred[1][0] + wred[2][0] + wred[3][0]) / (float)N_NODES;
        float s1 = (wred[0][1] + wred[1][1] + wred[2][1] + wred[3][1]) / (float)N_NODES;
        float m = fmaxf(s0, s1);
        float e0 = __expf(s0 - m), e1 = __expf(s1 - m);
        float inv = 1.0f / (e0 + e1);
        beta[0] = e0 * inv;
        beta[1] = e1 * inv;
    }
}

// out = beta0 * geo_mean + beta1 * trans, reading bf16 z.
__global__ void combine_kernel(const unsigned short* __restrict__ zb,
                               const float* __restrict__ beta,
                               float* __restrict__ out) {
    int gid = blockIdx.x * 256 + threadIdx.x;   // 8 elements per thread
    float b0 = beta[0];
    float b1 = beta[1];
    uint4 g = *(const uint4*)&zb[(size_t)gid * 8];
    uint4 tr = *(const uint4*)&zb[(size_t)N_NODES * DIM + (size_t)gid * 8];
    float4 o0, o1;
    o0.x = b0 * __uint_as_float(g.x << 16) + b1 * __uint_as_float(tr.x << 16);
    o0.y = b0 * __uint_as_float(g.x & 0xFFFF0000u) + b1 * __uint_as_float(tr.x & 0xFFFF0000u);
    o0.z = b0 * __uint_as_float(g.y << 16) + b1 * __uint_as_float(tr.y << 16);
    o0.w = b0 * __uint_as_float(g.y & 0xFFFF0000u) + b1 * __uint_as_float(tr.y & 0xFFFF0000u);
    o1.x = b0 * __uint_as_float(g.z << 16) + b1 * __uint_as_float(tr.z << 16);
    o1.y = b0 * __uint_as_float(g.z & 0xFFFF0000u) + b1 * __uint_as_float(tr.z & 0xFFFF0000u);
    o1.z = b0 * __uint_as_float(g.w << 16) + b1 * __uint_as_float(tr.w << 16);
    o1.w = b0 * __uint_as_float(g.w & 0xFFFF0000u) + b1 * __uint_as_float(tr.w & 0xFFFF0000u);
    *(float4*)&out[(size_t)gid * 8] = o0;
    *(float4*)&out[(size_t)gid * 8 + 4] = o1;
}

extern "C" void kernel_launch(void* const* d_in, const int* in_sizes, int n_in,
                              void* d_out, int out_size, void* d_ws, size_t ws_size,
                              hipStream_t stream) {
    const float* loc_feat = (const float*)d_in[0];
    const int* geo_src    = (const int*)d_in[1];
    const int* geo_dst    = (const int*)d_in[2];
    const int* trans_src  = (const int*)d_in[3];
    const int* trans_dst  = (const int*)d_in[4];
    const float* trans_w  = (const float*)d_in[5];
    const float* W1       = (const float*)d_in[6];
    const float* b1       = (const float*)d_in[7];
    const float* W2       = (const float*)d_in[8];
    float* out = (float*)d_out;

    // ws layout (4B units): [gcount 2*NBINS][gbin NBINS*CAP int][tbin NBINS*CAP int2]
    //   [partials 2*3125][beta 2][W1p 16384 u16][featb N*64 u16][zb 2N*64 u16]  ~55 MB
    int*   gcount   = (int*)d_ws;
    int*   gbin     = gcount + 2 * NBINS;
    int2*  tbin     = (int2*)(gbin + (size_t)NBINS * CAP);
    float* partials = (float*)(tbin + (size_t)NBINS * CAP);
    float* beta     = partials + 2 * MLP_ROWBLOCKS;
    unsigned short* W1p   = (unsigned short*)(beta + 2);
    unsigned short* featb = W1p + 16384;
    unsigned short* zb    = featb + (size_t)N_NODES * DIM;

    hipMemsetAsync(gcount, 0, 2 * NBINS * sizeof(int), stream);

    pack_feat_kernel<<<(N_NODES * DIM / 4) / 256, 256, 0, stream>>>(loc_feat, featb);
    pack_w1_kernel<<<64, 256, 0, stream>>>(W1, W1p);
    bin_fill_kernel<<<2 * FILL_BLOCKS, 512, 0, stream>>>(geo_src, geo_dst, trans_src,
                                                         trans_dst, trans_w,
                                                         gcount, gbin, tbin);
    aggregate_kernel<<<2 * NBINS, 256, 0, stream>>>(featb, gbin, tbin, gcount, zb);
    mlp_mfma_kernel<<<MLP_ROWBLOCKS, 256, 0, stream>>>(zb, W1p, b1, W2, partials);
    beta_kernel<<<1, 256, 0, stream>>>(partials, beta);
    combine_kernel<<<(N_NODES * DIM / 8) / 256, 256, 0, stream>>>(zb, beta, out);
}